// Round 9
// baseline (6337.790 us; speedup 1.0000x reference)
//
#include <hip/hip_runtime.h>
#include <math.h>

// ---------------------------------------------------------------------------
// BivariateNormalAttention pipeline.
// Round 8: conv1/conv2 — B operand moved OUT of LDS back to direct global
//   reads (L2-resident wp, 1KB contiguous per wave-read), register-prefetched
//   one tap ahead (R2's proven pattern; L1 demand now ~32B/cyc < 64 ceiling
//   with 2x 128-co tiles/CU). This removes ALL intra-chunk barriers (sA is
//   read-only per chunk): 2 barriers/chunk instead of 10, so A-frag LDS reads
//   de-phase across waves and hide under MFMA.
//   LDS = sA only (43008B static), 2 blocks/CU, __launch_bounds__(256,2).
//   MFMA 16x16x32_bf16, 3-product hi/lo split (AhBh + AhBl + AlBh).
// ---------------------------------------------------------------------------

typedef __attribute__((ext_vector_type(8))) short short8v;
typedef __attribute__((ext_vector_type(4))) float f32x4;

__device__ __forceinline__ void split_bf16(float f, unsigned int& hi, unsigned int& lo)
{
    unsigned int u = __float_as_uint(f);
    hi = u >> 16;                                    // truncated bf16 hi
    float hif = __uint_as_float(u & 0xffff0000u);
    lo = __float_as_uint(f - hif) >> 16;             // residual, truncated
}

__device__ __forceinline__ void gld16(const void* g, void* l)
{
    __builtin_amdgcn_global_load_lds(
        (const __attribute__((address_space(1))) unsigned int*)g,
        (__attribute__((address_space(3))) unsigned int*)l, 16, 0, 0);
}

__global__ void zero_kernel(float* z) { z[threadIdx.x] = 0.f; }

// wp[y2][ch][tap][pl2][co128][k32] u16, fully linear (no swizzle — B is read
// from global now, LDS bank layout irrelevant).
__global__ __launch_bounds__(256)
void prep_w_kernel(const float* __restrict__ w, unsigned short* __restrict__ wp, int CIN)
{
    int idx = blockIdx.x * 256 + threadIdx.x;
    int NCH = CIN >> 5;
    int total = 2 * NCH * 9 * 2 * 128 * 32;
    if (idx >= total) return;
    int kk = idx & 31;
    int co = (idx >> 5) & 127;
    int pl = (idx >> 12) & 1;
    int rest = idx >> 13;            // (y*NCH + ch)*9 + tap
    int tap = rest % 9;
    rest /= 9;
    int ch = rest % NCH;
    int y = rest / NCH;
    int ci = ch * 32 + kk;
    int cog = y * 128 + co;
    float f = w[((size_t)cog * CIN + ci) * 9 + tap];
    unsigned int hi, lo;
    split_bf16(f, hi, lo);
    wp[idx] = (unsigned short)(pl ? lo : hi);
}

// x[b][512][112][112] f32 -> xs[b][16ch][2pl][112][112][32ci] bf16,
// quarters pre-swizzled by pixel: qp = q ^ ((18*gy+gx+19)>>1 & 3)
__global__ __launch_bounds__(256)
void presplit_x_kernel(const float* __restrict__ x, unsigned short* __restrict__ xs)
{
    const int gy = blockIdx.x, ch = blockIdx.y, b = blockIdx.z;
    const int tid = threadIdx.x;
    __shared__ float s[32][113];
    for (int i = tid; i < 32 * 112; i += 256) {
        int ci = i / 112, xx = i - ci * 112;
        s[ci][xx] = x[(((size_t)(b * 16 + ch) * 32 + ci) * 112 + gy) * 112 + xx];
    }
    __syncthreads();
    unsigned int* oh = (unsigned int*)(xs + ((size_t)(b * 16 + ch) * 2 * 12544 + (size_t)gy * 112) * 32);
    unsigned int* ol = oh + 12544 * 16;   // plane stride in u32: 12544*32/2
    for (int i = tid; i < 112 * 16; i += 256) {
        int px = i >> 4, t = i & 15;          // t = u32 slot within 64B row
        int qp = t >> 2, ep = t & 3;
        int sw = ((18 * gy + px + 19) >> 1) & 3;
        int q = qp ^ sw;
        int ci0 = q * 8 + ep * 2;
        float f0 = s[ci0][px], f1 = s[ci0 + 1][px];
        unsigned int h0, l0, h1, l1;
        split_bf16(f0, h0, l0);
        split_bf16(f1, h1, l1);
        oh[(size_t)px * 16 + t] = h0 | (h1 << 16);
        ol[(size_t)px * 16 + t] = l0 | (l1 << 16);
    }
}

// POOL=false: conv1, input xs (pre-split x), writes h1s (pre-split layout).
// POOL=true : conv2, input h1s, writes pooled fp32 [B,256,7,7].
template<int CIN, bool POOL>
__global__ __launch_bounds__(256, 2)
void conv_mfma_kernel(const unsigned short* __restrict__ xs,
                      const unsigned short* __restrict__ wp,
                      const float* __restrict__ gam, const float* __restrict__ bet,
                      void* __restrict__ out_, const float* __restrict__ zerob)
{
    constexpr int NCH = CIN >> 5;
    constexpr int NT = NCH * 9;
    __shared__ __align__(16) char sA[43008];   // [2pl][336px][64B] (324 used)

    const int tid = threadIdx.x;
    const int lane = tid & 63;
    const int wv = tid >> 6;
    const int wvm = wv >> 1, ng = wv & 1;
    const int m = lane & 15, kg = lane >> 4;
    const int ty = blockIdx.x / 7, tx = blockIdx.x % 7;
    const int yb = blockIdx.y;
    const int b = blockIdx.z;

    // ---- A staging geometry: 42 wave-issues of 1KB, round-robin over 4 waves
    int aoff[11];
    unsigned adst[11];
    #pragma unroll
    for (int k2 = 0; k2 < 11; ++k2) {
        int j = wv + 4 * k2;
        aoff[k2] = -1; adst[k2] = 0;
        if (j < 42) {
            int pl = j / 21, jj = j - pl * 21;
            int px = jj * 16 + (lane >> 2);
            int py = px / 18, pxx = px - py * 18;
            int gy = ty * 16 + py - 1, gx = tx * 16 + pxx - 1;
            bool valid = (px < 324) && ((unsigned)gy < 112u) && ((unsigned)gx < 112u);
            aoff[k2] = valid ? (pl * 802816 + ((gy * 112 + gx) << 6) + ((lane & 3) << 4)) : -1;
            adst[k2] = pl * 21504 + jj * 1024;
        }
    }
    const char* zb = (const char*)zerob + ((lane & 3) << 4);

    auto issueA = [&](int ch) {
        const char* xbase = (const char*)xs + (size_t)(b * NCH + ch) * 1605632;
        #pragma unroll
        for (int k2 = 0; k2 < 11; ++k2) {
            if (wv + 4 * k2 < 42) {
                const char* g = (aoff[k2] >= 0) ? (xbase + aoff[k2]) : zb;
                gld16(g, sA + adst[k2]);
            }
        }
    };

    // ---- B direct-global base: per (ch,tap) a 16KB block; this lane's slice
    const char* wbase = (const char*)wp + (size_t)yb * ((size_t)NCH * 9 * 16384)
                        + ng * 4096 + m * 64 + kg * 16;
    short8v Bh[4], Bl[4], Bh2[4], Bl2[4];
    auto loadB = [&](int flat, short8v* BH, short8v* BL) {
        const char* gb = wbase + (size_t)flat * 16384;
        #pragma unroll
        for (int nf = 0; nf < 4; ++nf) {
            BH[nf] = *(const short8v*)(gb + nf * 1024);
            BL[nf] = *(const short8v*)(gb + 8192 + nf * 1024);
        }
    };

    f32x4 acc[8][4];
    #pragma unroll
    for (int i = 0; i < 8; ++i)
        #pragma unroll
        for (int j = 0; j < 4; ++j)
            acc[i][j] = (f32x4){0.f, 0.f, 0.f, 0.f};

    issueA(0);
    loadB(0, Bh, Bl);
    asm volatile("s_waitcnt vmcnt(0)" ::: "memory");
    __syncthreads();

    for (int ch = 0; ch < NCH; ++ch) {
        #pragma unroll
        for (int tap = 0; tap < 9; ++tap) {
            const int flat = ch * 9 + tap;
            if (flat + 1 < NT) loadB(flat + 1, Bh2, Bl2);   // one full tap ahead
            const int ky = tap / 3, kx = tap % 3;
            #pragma unroll
            for (int mf = 0; mf < 8; ++mf) {
                int ap = (wvm * 8 + mf + ky) * 18 + kx + m;
                int off = ap * 64 + ((kg ^ ((ap >> 1) & 3)) << 4);
                short8v Ah = *(const short8v*)(sA + off);
                short8v Al = *(const short8v*)(sA + 21504 + off);
                #pragma unroll
                for (int nf = 0; nf < 4; ++nf) {
                    acc[mf][nf] = __builtin_amdgcn_mfma_f32_16x16x32_bf16(Ah, Bh[nf], acc[mf][nf], 0, 0, 0);
                    acc[mf][nf] = __builtin_amdgcn_mfma_f32_16x16x32_bf16(Ah, Bl[nf], acc[mf][nf], 0, 0, 0);
                    acc[mf][nf] = __builtin_amdgcn_mfma_f32_16x16x32_bf16(Al, Bh[nf], acc[mf][nf], 0, 0, 0);
                }
            }
            #pragma unroll
            for (int nf = 0; nf < 4; ++nf) { Bh[nf] = Bh2[nf]; Bl[nf] = Bl2[nf]; }
        }
        // chunk edge: only 2 barriers per chunk (sA read-only within chunk)
        __syncthreads();                     // all waves done reading sA
        if (ch + 1 < NCH) issueA(ch + 1);
        asm volatile("s_waitcnt vmcnt(0)" ::: "memory");
        __syncthreads();                     // staged sA visible to all waves
    }

    const float kRS = 1.0f / sqrtf(1.0f + 1e-5f);

    if (!POOL) {
        // write h1s[b][ch2 8][pl2][gy][gx][32] bf16, pixel-swizzled quarters
        unsigned short* h1s = (unsigned short*)out_;
        #pragma unroll
        for (int mf = 0; mf < 8; ++mf) {
            int gy = ty * 16 + wvm * 8 + mf;
            #pragma unroll
            for (int nf = 0; nf < 4; ++nf) {
                int co = yb * 128 + ng * 64 + nf * 16 + m;
                float sc = gam[co] * kRS, bi = bet[co];
                int ch2 = co >> 5, sl = co & 31, q = sl >> 3, e = sl & 7;
                size_t base2 = (size_t)(b * 8 + ch2) * 802816;   // u16 per (b,ch2)
                #pragma unroll
                for (int r = 0; r < 4; ++r) {
                    int gx = tx * 16 + kg * 4 + r;
                    float v = fmaxf(fmaf(acc[mf][nf][r], sc, bi), 0.f);
                    unsigned int hi, lo;
                    split_bf16(v, hi, lo);
                    int sw = ((18 * gy + gx + 19) >> 1) & 3;
                    size_t po = base2 + ((size_t)gy * 112 + gx) * 32 + (size_t)((q ^ sw) * 8 + e);
                    h1s[po] = (unsigned short)hi;
                    h1s[po + 401408] = (unsigned short)lo;
                }
            }
        }
    } else {
        // fused BN+ReLU + 16x16 avg pool (tile == pool window)
        __syncthreads();                      // all waves past the last barrier
        float* spool = (float*)sA;            // 4 waves x 4 nf x 16 co floats
        #pragma unroll
        for (int nf = 0; nf < 4; ++nf) {
            int co = yb * 128 + ng * 64 + nf * 16 + m;
            float sc = gam[co] * kRS, bi = bet[co];
            float s = 0.f;
            #pragma unroll
            for (int mf = 0; mf < 8; ++mf)
                #pragma unroll
                for (int r = 0; r < 4; ++r)
                    s += fmaxf(fmaf(acc[mf][nf][r], sc, bi), 0.f);
            s += __shfl_xor(s, 16);
            s += __shfl_xor(s, 32);
            if (lane < 16) spool[(wv * 4 + nf) * 16 + lane] = s;
        }
        __syncthreads();
        if (tid < 128) {
            // tid = ngx*64 + nf*16 + m : co within the yb half
            int ngx = tid >> 6, rem = tid & 63;
            int nf = rem >> 4, mm = rem & 15;
            float s = spool[(ngx * 4 + nf) * 16 + mm] + spool[((2 + ngx) * 4 + nf) * 16 + mm];
            float* p1o = (float*)out_;
            p1o[(((size_t)b * 256 + yb * 128 + tid) * 7 + ty) * 7 + tx] = s * (1.f / 256.f);
        }
    }
}

// ---------------- small downstream stages (unchanged) ----------------------

template<int CIN>
__global__ __launch_bounds__(256)
void conv_small_kernel(const float* __restrict__ in, const float* __restrict__ w,
                       const float* __restrict__ gam, const float* __restrict__ bet,
                       float* __restrict__ out, int CO_TOT)
{
    const int co0 = blockIdx.x * 16;
    const int b = blockIdx.y;
    const int tid = threadIdx.x;
    const int px = tid & 63;
    const int wg = tid >> 6;
    const int py = px / 7, pxx = px - py * 7;
    const bool act = px < 49;

    __shared__ float s_in[64][9][9];
    __shared__ float s_w[64][16][9];

    float acc[4] = {0.f, 0.f, 0.f, 0.f};

    for (int ci0 = 0; ci0 < CIN; ci0 += 64) {
        __syncthreads();
        for (int idx = tid; idx < 64 * 81; idx += 256) {
            int ci = idx / 81;
            int rem = idx - ci * 81;
            int r = rem / 9, c = rem - (rem / 9) * 9;
            float v = 0.f;
            if (r >= 1 && r <= 7 && c >= 1 && c <= 7)
                v = in[((size_t)(b * CIN + ci0 + ci) * 7 + (r - 1)) * 7 + (c - 1)];
            s_in[ci][r][c] = v;
        }
        for (int idx = tid; idx < 64 * 16 * 9; idx += 256) {
            int co = idx / 576;
            int rem = idx - co * 576;
            int ci = rem / 9, tap = rem - (rem / 9) * 9;
            s_w[ci][co][tap] = w[((size_t)(co0 + co) * CIN + ci0 + ci) * 9 + tap];
        }
        __syncthreads();
        if (act) {
            for (int ci = 0; ci < 64; ++ci) {
                #pragma unroll
                for (int ky = 0; ky < 3; ++ky)
                    #pragma unroll
                    for (int kx = 0; kx < 3; ++kx) {
                        float v = s_in[ci][py + ky][pxx + kx];
                        #pragma unroll
                        for (int j = 0; j < 4; ++j)
                            acc[j] = fmaf(v, s_w[ci][wg * 4 + j][ky * 3 + kx], acc[j]);
                    }
            }
        }
    }
    if (act) {
        const float kRS = 1.0f / sqrtf(1.0f + 1e-5f);
        #pragma unroll
        for (int j = 0; j < 4; ++j) {
            int cog = co0 + wg * 4 + j;
            float v = fmaxf(fmaf(acc[j], gam[cog] * kRS, bet[cog]), 0.f);
            out[(size_t)(b * CO_TOT + cog) * 49 + py * 7 + pxx] = v;
        }
    }
}

__global__ void pool3x3_kernel(const float* __restrict__ in, float* __restrict__ out)
{
    int o = blockIdx.x * 256 + threadIdx.x;
    if (o >= 16 * 128 * 9) return;
    int xo = o % 3;
    int yo = (o / 3) % 3;
    int bc = o / 9;
    const float* p = in + (size_t)bc * 49;
    float s = 0.f;
    #pragma unroll
    for (int ky = 0; ky < 3; ++ky)
        #pragma unroll
        for (int kx = 0; kx < 3; ++kx)
            s += p[(yo * 2 + ky) * 7 + xo * 2 + kx];
    out[o] = s * (1.0f / 9.0f);
}

__global__ __launch_bounds__(256)
void conv5_kernel(const float* __restrict__ in, const float* __restrict__ w,
                  const float* __restrict__ gam, const float* __restrict__ bet,
                  float* __restrict__ out)
{
    const int co0 = blockIdx.x * 16;
    const int b = blockIdx.y;
    const int tid = threadIdx.x;
    __shared__ float s_in[128][5][5];
    __shared__ float s_w[64][16][9];

    for (int idx = tid; idx < 128 * 25; idx += 256) {
        int ci = idx / 25;
        int rem = idx - ci * 25;
        int r = rem / 5, c = rem - (rem / 5) * 5;
        float v = 0.f;
        if (r >= 1 && r <= 3 && c >= 1 && c <= 3)
            v = in[((size_t)(b * 128 + ci) * 3 + (r - 1)) * 3 + (c - 1)];
        s_in[ci][r][c] = v;
    }

    float acc = 0.f;
    const int co = tid / 9;
    const int px = tid - co * 9;
    const int pyy = px / 3, pxx = px - pyy * 3;
    const bool act = tid < 144;

    for (int ci0 = 0; ci0 < 128; ci0 += 64) {
        __syncthreads();
        for (int idx = tid; idx < 64 * 16 * 9; idx += 256) {
            int c2 = idx / 576;
            int rem = idx - c2 * 576;
            int ci = rem / 9, tap = rem - (rem / 9) * 9;
            s_w[ci][c2][tap] = w[((size_t)(co0 + c2) * 128 + ci0 + ci) * 9 + tap];
        }
        __syncthreads();
        if (act) {
            for (int ci = 0; ci < 64; ++ci) {
                #pragma unroll
                for (int ky = 0; ky < 3; ++ky)
                    #pragma unroll
                    for (int kx = 0; kx < 3; ++kx)
                        acc = fmaf(s_in[ci0 + ci][pyy + ky][pxx + kx],
                                   s_w[ci][co][ky * 3 + kx], acc);
            }
        }
    }
    if (act) {
        const float kRS = 1.0f / sqrtf(1.0f + 1e-5f);
        int cog = co0 + co;
        out[(size_t)(b * 64 + cog) * 9 + px] =
            fmaxf(fmaf(acc, gam[cog] * kRS, bet[cog]), 0.f);
    }
}

__global__ void fc_kernel(const float* __restrict__ h5, const float* __restrict__ wfc,
                          float* __restrict__ feats)
{
    int o = blockIdx.x * 256 + threadIdx.x;
    if (o >= 16 * 128) return;
    int b = o >> 7, j = o & 127;
    const float* hp = h5 + b * 576;
    const float* wp = wfc + j * 576;
    float s = 0.f;
    for (int k = 0; k < 576; ++k) s = fmaf(hp[k], wp[k], s);
    feats[o] = s;
}

__global__ __launch_bounds__(256)
void attn_kernel(const float* __restrict__ feats, const float* __restrict__ mixw,
                 float* __restrict__ out)
{
    const int bo = blockIdx.x;
    const int b = bo >> 3, o = bo & 7;
    const int tid = threadIdx.x;
    __shared__ float s_att[4][3136];
    __shared__ float s_red[4];

    float mv[4];
    float mmax = -1e30f;
    #pragma unroll
    for (int g = 0; g < 4; ++g) { mv[g] = mixw[o * 4 + g]; mmax = fmaxf(mmax, mv[g]); }
    float msum = 0.f;
    #pragma unroll
    for (int g = 0; g < 4; ++g) { mv[g] = expf(mv[g] - mmax); msum += mv[g]; }
    #pragma unroll
    for (int g = 0; g < 4; ++g) mv[g] /= msum;

    const float LOG_R = 1.0986122886681098f;
    float winv[4];
    for (int g = 0; g < 4; ++g) {
        float f0 = feats[b * 128 + o * 16 + g * 4 + 0];
        float f1 = feats[b * 128 + o * 16 + g * 4 + 1];
        float f2 = feats[b * 128 + o * 16 + g * 4 + 2];
        float f3 = feats[b * 128 + o * 16 + g * 4 + 3];
        float m_x = 55.f / (1.f + expf(-f0));
        float m_y = 55.f / (1.f + expf(-f1));
        float r = expf((2.f / (1.f + expf(-f2)) - 1.f) * LOG_R);
        float rho = 1.6f / (1.f + expf(-f3)) - 0.8f;
        float denom = (-0.5f / (1.f - rho * rho)) * (1.f / 3136.f);
        float rin = 1.f / r;

        float ssum = 0.f;
        for (int p = tid; p < 3136; p += 256) {
            int i = p / 56;
            int j = p - i * 56;
            float dx = m_x - (float)i;
            float dy = m_y - (float)j;
            float quad = dx * dx * r + dy * dy * rin - 2.f * rho * dx * dy;
            float e = expf(denom * quad);
            s_att[g][p] = e;
            ssum += e;
        }
        #pragma unroll
        for (int off = 32; off > 0; off >>= 1) ssum += __shfl_down(ssum, off);
        if ((tid & 63) == 0) s_red[tid >> 6] = ssum;
        __syncthreads();
        winv[g] = mv[g] / (s_red[0] + s_red[1] + s_red[2] + s_red[3]);
        __syncthreads();
    }

    for (int p = tid; p < 3136; p += 256) {
        float v = 0.f;
        #pragma unroll
        for (int g = 0; g < 4; ++g) v += s_att[g][p] * winv[g];
        out[(size_t)bo * 3136 + p] = v;
    }
}

// ---------------------------------------------------------------------------

extern "C" void kernel_launch(void* const* d_in, const int* in_sizes, int n_in,
                              void* d_out, int out_size, void* d_ws, size_t ws_size,
                              hipStream_t stream)
{
    const float* x    = (const float*)d_in[0];
    const float* w1   = (const float*)d_in[1];
    const float* g1   = (const float*)d_in[2];
    const float* b1   = (const float*)d_in[3];
    const float* w2   = (const float*)d_in[4];
    const float* g2   = (const float*)d_in[5];
    const float* b2   = (const float*)d_in[6];
    const float* w3   = (const float*)d_in[7];
    const float* g3   = (const float*)d_in[8];
    const float* b3   = (const float*)d_in[9];
    const float* w4   = (const float*)d_in[10];
    const float* g4   = (const float*)d_in[11];
    const float* b4   = (const float*)d_in[12];
    const float* w5   = (const float*)d_in[13];
    const float* g5   = (const float*)d_in[14];
    const float* b5   = (const float*)d_in[15];
    const float* wfc  = (const float*)d_in[16];
    const float* mixw = (const float*)d_in[17];
    float* outp = (float*)d_out;

    // workspace layout (bytes)
    char* wsb = (char*)d_ws;
    unsigned short* wp = (unsigned short*)wsb;   wsb += (size_t)2359296 * 2;      // 4.7MB (reused)
    unsigned short* xs = (unsigned short*)wsb;   wsb += (size_t)16*16*2*12544*32*2;  // 411MB
    unsigned short* h1s = (unsigned short*)wsb;  wsb += (size_t)16*8*2*12544*32*2;   // 205.5MB
    float* p1 = (float*)wsb;  wsb += 200704 * 4;
    float* h3 = (float*)wsb;  wsb += 100352 * 4;
    float* h4 = (float*)wsb;  wsb += 100352 * 4;
    float* p2 = (float*)wsb;  wsb += 18432 * 4;
    float* h5 = (float*)wsb;  wsb += 9216 * 4;
    float* fts = (float*)wsb; wsb += 2048 * 4;
    float* zerob = (float*)wsb; wsb += 64 * 4;

    zero_kernel<<<1, 64, 0, stream>>>(zerob);
    presplit_x_kernel<<<dim3(112, 16, 16), 256, 0, stream>>>(x, xs);

    prep_w_kernel<<<9216, 256, 0, stream>>>(w1, wp, 512);
    conv_mfma_kernel<512, false><<<dim3(49, 2, 16), 256, 0, stream>>>(xs, wp, g1, b1, h1s, zerob);

    prep_w_kernel<<<4608, 256, 0, stream>>>(w2, wp, 256);
    conv_mfma_kernel<256, true><<<dim3(49, 2, 16), 256, 0, stream>>>(h1s, wp, g2, b2, p1, zerob);

    conv_small_kernel<256><<<dim3(8, 16), 256, 0, stream>>>(p1, w3, g3, b3, h3, 128);
    conv_small_kernel<128><<<dim3(8, 16), 256, 0, stream>>>(h3, w4, g4, b4, h4, 128);

    pool3x3_kernel<<<72, 256, 0, stream>>>(h4, p2);
    conv5_kernel<<<dim3(4, 16), 256, 0, stream>>>(p2, w5, g5, b5, h5);
    fc_kernel<<<8, 256, 0, stream>>>(h5, wfc, fts);
    attn_kernel<<<128, 256, 0, stream>>>(fts, mixw, outp);
}

// Round 10
// 4699.184 us; speedup vs baseline: 1.3487x; 1.3487x over previous
//
#include <hip/hip_runtime.h>
#include <math.h>

// ---------------------------------------------------------------------------
// BivariateNormalAttention pipeline.
// Round 9: R8's barrier-free direct-global-B structure, SPILL-FIXED:
//   B per tap split into two nf-halves (16 VGPR each, 32 live max vs R8's 64
//   which spilled to scratch -> 8GB WRITE_SIZE). Per tap:
//     [B-half0 preloaded] -> issue B-half1 -> 48 MFMA w/ half0
//     -> issue next-tap B-half0 -> 48 MFMA w/ half1.
//   Zero intra-chunk barriers (sA read-only per chunk; 2 barriers/chunk).
//   A-frags re-read per half (32 b128/wave/tap, LDS pipe 3072 < 3725 cyc MFMA).
//   LDS = sA only (43008B static), 2 blocks/CU, __launch_bounds__(256,2).
//   MFMA 16x16x32_bf16, 3-product hi/lo split (AhBh + AhBl + AlBh).
// ---------------------------------------------------------------------------

typedef __attribute__((ext_vector_type(8))) short short8v;
typedef __attribute__((ext_vector_type(4))) float f32x4;

__device__ __forceinline__ void split_bf16(float f, unsigned int& hi, unsigned int& lo)
{
    unsigned int u = __float_as_uint(f);
    hi = u >> 16;                                    // truncated bf16 hi
    float hif = __uint_as_float(u & 0xffff0000u);
    lo = __float_as_uint(f - hif) >> 16;             // residual, truncated
}

__device__ __forceinline__ void gld16(const void* g, void* l)
{
    __builtin_amdgcn_global_load_lds(
        (const __attribute__((address_space(1))) unsigned int*)g,
        (__attribute__((address_space(3))) unsigned int*)l, 16, 0, 0);
}

__global__ void zero_kernel(float* z) { z[threadIdx.x] = 0.f; }

// wp[y2][ch][tap][pl2][co128][k32] u16, fully linear (B read from global).
__global__ __launch_bounds__(256)
void prep_w_kernel(const float* __restrict__ w, unsigned short* __restrict__ wp, int CIN)
{
    int idx = blockIdx.x * 256 + threadIdx.x;
    int NCH = CIN >> 5;
    int total = 2 * NCH * 9 * 2 * 128 * 32;
    if (idx >= total) return;
    int kk = idx & 31;
    int co = (idx >> 5) & 127;
    int pl = (idx >> 12) & 1;
    int rest = idx >> 13;            // (y*NCH + ch)*9 + tap
    int tap = rest % 9;
    rest /= 9;
    int ch = rest % NCH;
    int y = rest / NCH;
    int ci = ch * 32 + kk;
    int cog = y * 128 + co;
    float f = w[((size_t)cog * CIN + ci) * 9 + tap];
    unsigned int hi, lo;
    split_bf16(f, hi, lo);
    wp[idx] = (unsigned short)(pl ? lo : hi);
}

// x[b][512][112][112] f32 -> xs[b][16ch][2pl][112][112][32ci] bf16,
// quarters pre-swizzled by pixel: qp = q ^ ((18*gy+gx+19)>>1 & 3)
__global__ __launch_bounds__(256)
void presplit_x_kernel(const float* __restrict__ x, unsigned short* __restrict__ xs)
{
    const int gy = blockIdx.x, ch = blockIdx.y, b = blockIdx.z;
    const int tid = threadIdx.x;
    __shared__ float s[32][113];
    for (int i = tid; i < 32 * 112; i += 256) {
        int ci = i / 112, xx = i - ci * 112;
        s[ci][xx] = x[(((size_t)(b * 16 + ch) * 32 + ci) * 112 + gy) * 112 + xx];
    }
    __syncthreads();
    unsigned int* oh = (unsigned int*)(xs + ((size_t)(b * 16 + ch) * 2 * 12544 + (size_t)gy * 112) * 32);
    unsigned int* ol = oh + 12544 * 16;   // plane stride in u32: 12544*32/2
    for (int i = tid; i < 112 * 16; i += 256) {
        int px = i >> 4, t = i & 15;          // t = u32 slot within 64B row
        int qp = t >> 2, ep = t & 3;
        int sw = ((18 * gy + px + 19) >> 1) & 3;
        int q = qp ^ sw;
        int ci0 = q * 8 + ep * 2;
        float f0 = s[ci0][px], f1 = s[ci0 + 1][px];
        unsigned int h0, l0, h1, l1;
        split_bf16(f0, h0, l0);
        split_bf16(f1, h1, l1);
        oh[(size_t)px * 16 + t] = h0 | (h1 << 16);
        ol[(size_t)px * 16 + t] = l0 | (l1 << 16);
    }
}

// POOL=false: conv1, input xs (pre-split x), writes h1s (pre-split layout).
// POOL=true : conv2, input h1s, writes pooled fp32 [B,256,7,7].
template<int CIN, bool POOL>
__global__ __launch_bounds__(256, 2)
void conv_mfma_kernel(const unsigned short* __restrict__ xs,
                      const unsigned short* __restrict__ wp,
                      const float* __restrict__ gam, const float* __restrict__ bet,
                      void* __restrict__ out_, const float* __restrict__ zerob)
{
    constexpr int NCH = CIN >> 5;
    constexpr int NT = NCH * 9;
    __shared__ __align__(16) char sA[43008];   // [2pl][336px][64B] (324 used)

    const int tid = threadIdx.x;
    const int lane = tid & 63;
    const int wv = tid >> 6;
    const int wvm = wv >> 1, ng = wv & 1;
    const int m = lane & 15, kg = lane >> 4;
    const int ty = blockIdx.x / 7, tx = blockIdx.x % 7;
    const int yb = blockIdx.y;
    const int b = blockIdx.z;

    // ---- A staging geometry: 42 wave-issues of 1KB, round-robin over 4 waves
    int aoff[11];
    unsigned adst[11];
    #pragma unroll
    for (int k2 = 0; k2 < 11; ++k2) {
        int j = wv + 4 * k2;
        aoff[k2] = -1; adst[k2] = 0;
        if (j < 42) {
            int pl = j / 21, jj = j - pl * 21;
            int px = jj * 16 + (lane >> 2);
            int py = px / 18, pxx = px - py * 18;
            int gy = ty * 16 + py - 1, gx = tx * 16 + pxx - 1;
            bool valid = (px < 324) && ((unsigned)gy < 112u) && ((unsigned)gx < 112u);
            aoff[k2] = valid ? (pl * 802816 + ((gy * 112 + gx) << 6) + ((lane & 3) << 4)) : -1;
            adst[k2] = pl * 21504 + jj * 1024;
        }
    }
    const char* zb = (const char*)zerob + ((lane & 3) << 4);

    auto issueA = [&](int ch) {
        const char* xbase = (const char*)xs + (size_t)(b * NCH + ch) * 1605632;
        #pragma unroll
        for (int k2 = 0; k2 < 11; ++k2) {
            if (wv + 4 * k2 < 42) {
                const char* g = (aoff[k2] >= 0) ? (xbase + aoff[k2]) : zb;
                gld16(g, sA + adst[k2]);
            }
        }
    };

    // ---- B direct-global: per (ch,tap) a 16KB block; lane slice for nf-half h
    //   hi frag (nf=h*2+j): flat*16384 + h*2048 + j*1024 ; lo at +8192
    const char* wbase = (const char*)wp + (size_t)yb * ((size_t)NCH * 9 * 16384)
                        + ng * 4096 + m * 64 + kg * 16;
    short8v B0h[2], B0l[2], B1h[2], B1l[2];
    auto loadBhalf = [&](int flat, int half, short8v* BH, short8v* BL) {
        const char* gb = wbase + (size_t)flat * 16384 + half * 2048;
        #pragma unroll
        for (int j2 = 0; j2 < 2; ++j2) {
            BH[j2] = *(const short8v*)(gb + j2 * 1024);
            BL[j2] = *(const short8v*)(gb + 8192 + j2 * 1024);
        }
    };

    f32x4 acc[8][4];
    #pragma unroll
    for (int i = 0; i < 8; ++i)
        #pragma unroll
        for (int j = 0; j < 4; ++j)
            acc[i][j] = (f32x4){0.f, 0.f, 0.f, 0.f};

    issueA(0);
    loadBhalf(0, 0, B0h, B0l);
    asm volatile("s_waitcnt vmcnt(0)" ::: "memory");
    __syncthreads();

    for (int ch = 0; ch < NCH; ++ch) {
        #pragma unroll
        for (int tap = 0; tap < 9; ++tap) {
            const int flat = ch * 9 + tap;
            const int ky = tap / 3, kx = tap % 3;
            // issue second half of this tap's B (used after first mf loop)
            loadBhalf(flat, 1, B1h, B1l);
            // ---- mf loop with half0 (nf 0,1)
            #pragma unroll
            for (int mf = 0; mf < 8; ++mf) {
                int ap = (wvm * 8 + mf + ky) * 18 + kx + m;
                int off = ap * 64 + ((kg ^ ((ap >> 1) & 3)) << 4);
                short8v Ah = *(const short8v*)(sA + off);
                short8v Al = *(const short8v*)(sA + 21504 + off);
                #pragma unroll
                for (int j2 = 0; j2 < 2; ++j2) {
                    acc[mf][j2] = __builtin_amdgcn_mfma_f32_16x16x32_bf16(Ah, B0h[j2], acc[mf][j2], 0, 0, 0);
                    acc[mf][j2] = __builtin_amdgcn_mfma_f32_16x16x32_bf16(Ah, B0l[j2], acc[mf][j2], 0, 0, 0);
                    acc[mf][j2] = __builtin_amdgcn_mfma_f32_16x16x32_bf16(Al, B0h[j2], acc[mf][j2], 0, 0, 0);
                }
            }
            // issue next tap's first half (used after second mf loop)
            if (flat + 1 < NT) loadBhalf(flat + 1, 0, B0h, B0l);
            // ---- mf loop with half1 (nf 2,3)
            #pragma unroll
            for (int mf = 0; mf < 8; ++mf) {
                int ap = (wvm * 8 + mf + ky) * 18 + kx + m;
                int off = ap * 64 + ((kg ^ ((ap >> 1) & 3)) << 4);
                short8v Ah = *(const short8v*)(sA + off);
                short8v Al = *(const short8v*)(sA + 21504 + off);
                #pragma unroll
                for (int j2 = 0; j2 < 2; ++j2) {
                    acc[mf][2 + j2] = __builtin_amdgcn_mfma_f32_16x16x32_bf16(Ah, B1h[j2], acc[mf][2 + j2], 0, 0, 0);
                    acc[mf][2 + j2] = __builtin_amdgcn_mfma_f32_16x16x32_bf16(Ah, B1l[j2], acc[mf][2 + j2], 0, 0, 0);
                    acc[mf][2 + j2] = __builtin_amdgcn_mfma_f32_16x16x32_bf16(Al, B1h[j2], acc[mf][2 + j2], 0, 0, 0);
                }
            }
        }
        // chunk edge: only 2 barriers per chunk (sA read-only within chunk)
        __syncthreads();                     // all waves done reading sA
        if (ch + 1 < NCH) issueA(ch + 1);
        asm volatile("s_waitcnt vmcnt(0)" ::: "memory");
        __syncthreads();                     // staged sA visible to all waves
    }

    const float kRS = 1.0f / sqrtf(1.0f + 1e-5f);

    if (!POOL) {
        // write h1s[b][ch2 8][pl2][gy][gx][32] bf16, pixel-swizzled quarters
        unsigned short* h1s = (unsigned short*)out_;
        #pragma unroll
        for (int mf = 0; mf < 8; ++mf) {
            int gy = ty * 16 + wvm * 8 + mf;
            #pragma unroll
            for (int nf = 0; nf < 4; ++nf) {
                int co = yb * 128 + ng * 64 + nf * 16 + m;
                float sc = gam[co] * kRS, bi = bet[co];
                int ch2 = co >> 5, sl = co & 31, q = sl >> 3, e = sl & 7;
                size_t base2 = (size_t)(b * 8 + ch2) * 802816;   // u16 per (b,ch2)
                #pragma unroll
                for (int r = 0; r < 4; ++r) {
                    int gx = tx * 16 + kg * 4 + r;
                    float v = fmaxf(fmaf(acc[mf][nf][r], sc, bi), 0.f);
                    unsigned int hi, lo;
                    split_bf16(v, hi, lo);
                    int sw = ((18 * gy + gx + 19) >> 1) & 3;
                    size_t po = base2 + ((size_t)gy * 112 + gx) * 32 + (size_t)((q ^ sw) * 8 + e);
                    h1s[po] = (unsigned short)hi;
                    h1s[po + 401408] = (unsigned short)lo;
                }
            }
        }
    } else {
        // fused BN+ReLU + 16x16 avg pool (tile == pool window)
        __syncthreads();                      // all waves past the last barrier
        float* spool = (float*)sA;            // 4 waves x 4 nf x 16 co floats
        #pragma unroll
        for (int nf = 0; nf < 4; ++nf) {
            int co = yb * 128 + ng * 64 + nf * 16 + m;
            float sc = gam[co] * kRS, bi = bet[co];
            float s = 0.f;
            #pragma unroll
            for (int mf = 0; mf < 8; ++mf)
                #pragma unroll
                for (int r = 0; r < 4; ++r)
                    s += fmaxf(fmaf(acc[mf][nf][r], sc, bi), 0.f);
            s += __shfl_xor(s, 16);
            s += __shfl_xor(s, 32);
            if (lane < 16) spool[(wv * 4 + nf) * 16 + lane] = s;
        }
        __syncthreads();
        if (tid < 128) {
            // tid = ngx*64 + nf*16 + m : co within the yb half
            int ngx = tid >> 6, rem = tid & 63;
            int nf = rem >> 4, mm = rem & 15;
            float s = spool[(ngx * 4 + nf) * 16 + mm] + spool[((2 + ngx) * 4 + nf) * 16 + mm];
            float* p1o = (float*)out_;
            p1o[(((size_t)b * 256 + yb * 128 + tid) * 7 + ty) * 7 + tx] = s * (1.f / 256.f);
        }
    }
}

// ---------------- small downstream stages (unchanged) ----------------------

template<int CIN>
__global__ __launch_bounds__(256)
void conv_small_kernel(const float* __restrict__ in, const float* __restrict__ w,
                       const float* __restrict__ gam, const float* __restrict__ bet,
                       float* __restrict__ out, int CO_TOT)
{
    const int co0 = blockIdx.x * 16;
    const int b = blockIdx.y;
    const int tid = threadIdx.x;
    const int px = tid & 63;
    const int wg = tid >> 6;
    const int py = px / 7, pxx = px - py * 7;
    const bool act = px < 49;

    __shared__ float s_in[64][9][9];
    __shared__ float s_w[64][16][9];

    float acc[4] = {0.f, 0.f, 0.f, 0.f};

    for (int ci0 = 0; ci0 < CIN; ci0 += 64) {
        __syncthreads();
        for (int idx = tid; idx < 64 * 81; idx += 256) {
            int ci = idx / 81;
            int rem = idx - ci * 81;
            int r = rem / 9, c = rem - (rem / 9) * 9;
            float v = 0.f;
            if (r >= 1 && r <= 7 && c >= 1 && c <= 7)
                v = in[((size_t)(b * CIN + ci0 + ci) * 7 + (r - 1)) * 7 + (c - 1)];
            s_in[ci][r][c] = v;
        }
        for (int idx = tid; idx < 64 * 16 * 9; idx += 256) {
            int co = idx / 576;
            int rem = idx - co * 576;
            int ci = rem / 9, tap = rem - (rem / 9) * 9;
            s_w[ci][co][tap] = w[((size_t)(co0 + co) * CIN + ci0 + ci) * 9 + tap];
        }
        __syncthreads();
        if (act) {
            for (int ci = 0; ci < 64; ++ci) {
                #pragma unroll
                for (int ky = 0; ky < 3; ++ky)
                    #pragma unroll
                    for (int kx = 0; kx < 3; ++kx) {
                        float v = s_in[ci][py + ky][pxx + kx];
                        #pragma unroll
                        for (int j = 0; j < 4; ++j)
                            acc[j] = fmaf(v, s_w[ci][wg * 4 + j][ky * 3 + kx], acc[j]);
                    }
            }
        }
    }
    if (act) {
        const float kRS = 1.0f / sqrtf(1.0f + 1e-5f);
        #pragma unroll
        for (int j = 0; j < 4; ++j) {
            int cog = co0 + wg * 4 + j;
            float v = fmaxf(fmaf(acc[j], gam[cog] * kRS, bet[cog]), 0.f);
            out[(size_t)(b * CO_TOT + cog) * 49 + py * 7 + pxx] = v;
        }
    }
}

__global__ void pool3x3_kernel(const float* __restrict__ in, float* __restrict__ out)
{
    int o = blockIdx.x * 256 + threadIdx.x;
    if (o >= 16 * 128 * 9) return;
    int xo = o % 3;
    int yo = (o / 3) % 3;
    int bc = o / 9;
    const float* p = in + (size_t)bc * 49;
    float s = 0.f;
    #pragma unroll
    for (int ky = 0; ky < 3; ++ky)
        #pragma unroll
        for (int kx = 0; kx < 3; ++kx)
            s += p[(yo * 2 + ky) * 7 + xo * 2 + kx];
    out[o] = s * (1.0f / 9.0f);
}

__global__ __launch_bounds__(256)
void conv5_kernel(const float* __restrict__ in, const float* __restrict__ w,
                  const float* __restrict__ gam, const float* __restrict__ bet,
                  float* __restrict__ out)
{
    const int co0 = blockIdx.x * 16;
    const int b = blockIdx.y;
    const int tid = threadIdx.x;
    __shared__ float s_in[128][5][5];
    __shared__ float s_w[64][16][9];

    for (int idx = tid; idx < 128 * 25; idx += 256) {
        int ci = idx / 25;
        int rem = idx - ci * 25;
        int r = rem / 5, c = rem - (rem / 5) * 5;
        float v = 0.f;
        if (r >= 1 && r <= 3 && c >= 1 && c <= 3)
            v = in[((size_t)(b * 128 + ci) * 3 + (r - 1)) * 3 + (c - 1)];
        s_in[ci][r][c] = v;
    }

    float acc = 0.f;
    const int co = tid / 9;
    const int px = tid - co * 9;
    const int pyy = px / 3, pxx = px - pyy * 3;
    const bool act = tid < 144;

    for (int ci0 = 0; ci0 < 128; ci0 += 64) {
        __syncthreads();
        for (int idx = tid; idx < 64 * 16 * 9; idx += 256) {
            int c2 = idx / 576;
            int rem = idx - c2 * 576;
            int ci = rem / 9, tap = rem - (rem / 9) * 9;
            s_w[ci][c2][tap] = w[((size_t)(co0 + c2) * 128 + ci0 + ci) * 9 + tap];
        }
        __syncthreads();
        if (act) {
            for (int ci = 0; ci < 64; ++ci) {
                #pragma unroll
                for (int ky = 0; ky < 3; ++ky)
                    #pragma unroll
                    for (int kx = 0; kx < 3; ++kx)
                        acc = fmaf(s_in[ci0 + ci][pyy + ky][pxx + kx],
                                   s_w[ci][co][ky * 3 + kx], acc);
            }
        }
    }
    if (act) {
        const float kRS = 1.0f / sqrtf(1.0f + 1e-5f);
        int cog = co0 + co;
        out[(size_t)(b * 64 + cog) * 9 + px] =
            fmaxf(fmaf(acc, gam[cog] * kRS, bet[cog]), 0.f);
    }
}

__global__ void fc_kernel(const float* __restrict__ h5, const float* __restrict__ wfc,
                          float* __restrict__ feats)
{
    int o = blockIdx.x * 256 + threadIdx.x;
    if (o >= 16 * 128) return;
    int b = o >> 7, j = o & 127;
    const float* hp = h5 + b * 576;
    const float* wp = wfc + j * 576;
    float s = 0.f;
    for (int k = 0; k < 576; ++k) s = fmaf(hp[k], wp[k], s);
    feats[o] = s;
}

__global__ __launch_bounds__(256)
void attn_kernel(const float* __restrict__ feats, const float* __restrict__ mixw,
                 float* __restrict__ out)
{
    const int bo = blockIdx.x;
    const int b = bo >> 3, o = bo & 7;
    const int tid = threadIdx.x;
    __shared__ float s_att[4][3136];
    __shared__ float s_red[4];

    float mv[4];
    float mmax = -1e30f;
    #pragma unroll
    for (int g = 0; g < 4; ++g) { mv[g] = mixw[o * 4 + g]; mmax = fmaxf(mmax, mv[g]); }
    float msum = 0.f;
    #pragma unroll
    for (int g = 0; g < 4; ++g) { mv[g] = expf(mv[g] - mmax); msum += mv[g]; }
    #pragma unroll
    for (int g = 0; g < 4; ++g) mv[g] /= msum;

    const float LOG_R = 1.0986122886681098f;
    float winv[4];
    for (int g = 0; g < 4; ++g) {
        float f0 = feats[b * 128 + o * 16 + g * 4 + 0];
        float f1 = feats[b * 128 + o * 16 + g * 4 + 1];
        float f2 = feats[b * 128 + o * 16 + g * 4 + 2];
        float f3 = feats[b * 128 + o * 16 + g * 4 + 3];
        float m_x = 55.f / (1.f + expf(-f0));
        float m_y = 55.f / (1.f + expf(-f1));
        float r = expf((2.f / (1.f + expf(-f2)) - 1.f) * LOG_R);
        float rho = 1.6f / (1.f + expf(-f3)) - 0.8f;
        float denom = (-0.5f / (1.f - rho * rho)) * (1.f / 3136.f);
        float rin = 1.f / r;

        float ssum = 0.f;
        for (int p = tid; p < 3136; p += 256) {
            int i = p / 56;
            int j = p - i * 56;
            float dx = m_x - (float)i;
            float dy = m_y - (float)j;
            float quad = dx * dx * r + dy * dy * rin - 2.f * rho * dx * dy;
            float e = expf(denom * quad);
            s_att[g][p] = e;
            ssum += e;
        }
        #pragma unroll
        for (int off = 32; off > 0; off >>= 1) ssum += __shfl_down(ssum, off);
        if ((tid & 63) == 0) s_red[tid >> 6] = ssum;
        __syncthreads();
        winv[g] = mv[g] / (s_red[0] + s_red[1] + s_red[2] + s_red[3]);
        __syncthreads();
    }

    for (int p = tid; p < 3136; p += 256) {
        float v = 0.f;
        #pragma unroll
        for (int g = 0; g < 4; ++g) v += s_att[g][p] * winv[g];
        out[(size_t)bo * 3136 + p] = v;
    }
}

// ---------------------------------------------------------------------------

extern "C" void kernel_launch(void* const* d_in, const int* in_sizes, int n_in,
                              void* d_out, int out_size, void* d_ws, size_t ws_size,
                              hipStream_t stream)
{
    const float* x    = (const float*)d_in[0];
    const float* w1   = (const float*)d_in[1];
    const float* g1   = (const float*)d_in[2];
    const float* b1   = (const float*)d_in[3];
    const float* w2   = (const float*)d_in[4];
    const float* g2   = (const float*)d_in[5];
    const float* b2   = (const float*)d_in[6];
    const float* w3   = (const float*)d_in[7];
    const float* g3   = (const float*)d_in[8];
    const float* b3   = (const float*)d_in[9];
    const float* w4   = (const float*)d_in[10];
    const float* g4   = (const float*)d_in[11];
    const float* b4   = (const float*)d_in[12];
    const float* w5   = (const float*)d_in[13];
    const float* g5   = (const float*)d_in[14];
    const float* b5   = (const float*)d_in[15];
    const float* wfc  = (const float*)d_in[16];
    const float* mixw = (const float*)d_in[17];
    float* outp = (float*)d_out;

    // workspace layout (bytes)
    char* wsb = (char*)d_ws;
    unsigned short* wp = (unsigned short*)wsb;   wsb += (size_t)2359296 * 2;      // 4.7MB (reused)
    unsigned short* xs = (unsigned short*)wsb;   wsb += (size_t)16*16*2*12544*32*2;  // 411MB
    unsigned short* h1s = (unsigned short*)wsb;  wsb += (size_t)16*8*2*12544*32*2;   // 205.5MB
    float* p1 = (float*)wsb;  wsb += 200704 * 4;
    float* h3 = (float*)wsb;  wsb += 100352 * 4;
    float* h4 = (float*)wsb;  wsb += 100352 * 4;
    float* p2 = (float*)wsb;  wsb += 18432 * 4;
    float* h5 = (float*)wsb;  wsb += 9216 * 4;
    float* fts = (float*)wsb; wsb += 2048 * 4;
    float* zerob = (float*)wsb; wsb += 64 * 4;

    zero_kernel<<<1, 64, 0, stream>>>(zerob);
    presplit_x_kernel<<<dim3(112, 16, 16), 256, 0, stream>>>(x, xs);

    prep_w_kernel<<<9216, 256, 0, stream>>>(w1, wp, 512);
    conv_mfma_kernel<512, false><<<dim3(49, 2, 16), 256, 0, stream>>>(xs, wp, g1, b1, h1s, zerob);

    prep_w_kernel<<<4608, 256, 0, stream>>>(w2, wp, 256);
    conv_mfma_kernel<256, true><<<dim3(49, 2, 16), 256, 0, stream>>>(h1s, wp, g2, b2, p1, zerob);

    conv_small_kernel<256><<<dim3(8, 16), 256, 0, stream>>>(p1, w3, g3, b3, h3, 128);
    conv_small_kernel<128><<<dim3(8, 16), 256, 0, stream>>>(h3, w4, g4, b4, h4, 128);

    pool3x3_kernel<<<72, 256, 0, stream>>>(h4, p2);
    conv5_kernel<<<dim3(4, 16), 256, 0, stream>>>(p2, w5, g5, b5, h5);
    fc_kernel<<<8, 256, 0, stream>>>(h5, wfc, fts);
    attn_kernel<<<128, 256, 0, stream>>>(fts, mixw, outp);
}

// Round 11
// 2235.617 us; speedup vs baseline: 2.8349x; 2.1020x over previous
//
#include <hip/hip_runtime.h>
#include <math.h>

// ---------------------------------------------------------------------------
// BivariateNormalAttention pipeline.
// Round 10: R7 structure EXACTLY (2 independent 4-wave blocks/CU, 2-tap B
//   staging in 2x16KB halves, 10 barriers/chunk, zero spill) with the MFMA
//   shape switched 16x16x32 -> 32x32x16 (4061 vs 3378 FLOP/cyc measured:
//   -17% matrix-pipe wall). Staging layouts (wp, xs, sA, sB) byte-identical;
//   only read addressing + intrinsic + epilogue mapping change.
//   Wave tile M128xN64 = 4x2 frags of 32x32; acc = 8 x f32x16 = 128 regs.
//   A/B: row|col = lane&31, k = (lane>>5)*8+j. C/D: col=lane&31,
//   row = (reg&3) + 8*(reg>>2) + 4*(lane>>5)   [m74/m101-verified].
//   MFMA 3-product hi/lo split (AhBh + AhBl + AlBh), same-acc chains at
//   distance 2 (interleaved across the two N-frags).
// ---------------------------------------------------------------------------

typedef __attribute__((ext_vector_type(8))) short short8v;
typedef __attribute__((ext_vector_type(16))) float f32x16;

__device__ __forceinline__ void split_bf16(float f, unsigned int& hi, unsigned int& lo)
{
    unsigned int u = __float_as_uint(f);
    hi = u >> 16;                                    // truncated bf16 hi
    float hif = __uint_as_float(u & 0xffff0000u);
    lo = __float_as_uint(f - hif) >> 16;             // residual, truncated
}

__device__ __forceinline__ void gld16(const void* g, void* l)
{
    __builtin_amdgcn_global_load_lds(
        (const __attribute__((address_space(1))) unsigned int*)g,
        (__attribute__((address_space(3))) unsigned int*)l, 16, 0, 0);
}

__global__ void zero_kernel(float* z) { z[threadIdx.x] = 0.f; }

// wp[y2][ch][tap][pl2][co128][k32] u16; within each co's 64B row the 16B
// quarters are pre-swizzled: phys quarter qp holds logical q = qp ^ ((co>>1)&3).
__global__ __launch_bounds__(256)
void prep_w_kernel(const float* __restrict__ w, unsigned short* __restrict__ wp, int CIN)
{
    int idx = blockIdx.x * 256 + threadIdx.x;
    int NCH = CIN >> 5;
    int total = 2 * NCH * 9 * 2 * 128 * 32;
    if (idx >= total) return;
    int kk = idx & 31;
    int co = (idx >> 5) & 127;
    int pl = (idx >> 12) & 1;
    int rest = idx >> 13;            // (y*NCH + ch)*9 + tap
    int tap = rest % 9;
    rest /= 9;
    int ch = rest % NCH;
    int y = rest / NCH;
    int qp = kk >> 3, e = kk & 7;
    int q = qp ^ ((co >> 1) & 3);
    int ci = ch * 32 + q * 8 + e;
    int cog = y * 128 + co;
    float f = w[((size_t)cog * CIN + ci) * 9 + tap];
    unsigned int hi, lo;
    split_bf16(f, hi, lo);
    wp[idx] = (unsigned short)(pl ? lo : hi);
}

// x[b][512][112][112] f32 -> xs[b][16ch][2pl][112][112][32ci] bf16,
// quarters pre-swizzled by pixel: qp = q ^ ((18*gy+gx+19)>>1 & 3)
__global__ __launch_bounds__(256)
void presplit_x_kernel(const float* __restrict__ x, unsigned short* __restrict__ xs)
{
    const int gy = blockIdx.x, ch = blockIdx.y, b = blockIdx.z;
    const int tid = threadIdx.x;
    __shared__ float s[32][113];
    for (int i = tid; i < 32 * 112; i += 256) {
        int ci = i / 112, xx = i - ci * 112;
        s[ci][xx] = x[(((size_t)(b * 16 + ch) * 32 + ci) * 112 + gy) * 112 + xx];
    }
    __syncthreads();
    unsigned int* oh = (unsigned int*)(xs + ((size_t)(b * 16 + ch) * 2 * 12544 + (size_t)gy * 112) * 32);
    unsigned int* ol = oh + 12544 * 16;   // plane stride in u32: 12544*32/2
    for (int i = tid; i < 112 * 16; i += 256) {
        int px = i >> 4, t = i & 15;          // t = u32 slot within 64B row
        int qp = t >> 2, ep = t & 3;
        int sw = ((18 * gy + px + 19) >> 1) & 3;
        int q = qp ^ sw;
        int ci0 = q * 8 + ep * 2;
        float f0 = s[ci0][px], f1 = s[ci0 + 1][px];
        unsigned int h0, l0, h1, l1;
        split_bf16(f0, h0, l0);
        split_bf16(f1, h1, l1);
        oh[(size_t)px * 16 + t] = h0 | (h1 << 16);
        ol[(size_t)px * 16 + t] = l0 | (l1 << 16);
    }
}

// POOL=false: conv1, input xs (pre-split x), writes h1s (pre-split layout).
// POOL=true : conv2, input h1s, writes pooled fp32 [B,256,7,7].
template<int CIN, bool POOL>
__global__ __launch_bounds__(256, 2)
void conv_mfma_kernel(const unsigned short* __restrict__ xs,
                      const unsigned short* __restrict__ wp,
                      const float* __restrict__ gam, const float* __restrict__ bet,
                      void* __restrict__ out_, const float* __restrict__ zerob)
{
    constexpr int NCH = CIN >> 5;
    extern __shared__ __align__(16) char smem[];   // 75776 B
    char* sA = smem;                 // 43008: [2pl][336px][64B] (324 used)
    char* sB = smem + 43008;         // 2 x 16384: [half][pl2][co128][64B]

    const int tid = threadIdx.x;
    const int lane = tid & 63;
    const int wv = tid >> 6;
    const int wvm = wv >> 1, ng = wv & 1;
    const int ty = blockIdx.x / 7, tx = blockIdx.x % 7;
    const int yb = blockIdx.y;
    const int b = blockIdx.z;

    // lane decomposition for 32x32 frags
    const int lx = lane & 15;            // x within tile row
    const int lyin = (lane >> 4) & 1;    // y within 2-row M-frag
    const int lk = lane >> 5;            // k 8-group selector
    const int lcol = lane & 31;          // B col / C col

    // ---- A staging geometry: 42 wave-issues of 1KB, round-robin over 4 waves
    int aoff[11];
    unsigned adst[11];
    #pragma unroll
    for (int k2 = 0; k2 < 11; ++k2) {
        int j = wv + 4 * k2;
        aoff[k2] = -1; adst[k2] = 0;
        if (j < 42) {
            int pl = j / 21, jj = j - pl * 21;
            int px = jj * 16 + (lane >> 2);
            int py = px / 18, pxx = px - py * 18;
            int gy = ty * 16 + py - 1, gx = tx * 16 + pxx - 1;
            bool valid = (px < 324) && ((unsigned)gy < 112u) && ((unsigned)gx < 112u);
            aoff[k2] = valid ? (pl * 802816 + ((gy * 112 + gx) << 6) + ((lane & 3) << 4)) : -1;
            adst[k2] = pl * 21504 + jj * 1024;
        }
    }
    const char* zb = (const char*)zerob + ((lane & 3) << 4);

    auto issueA = [&](int ch) {
        const char* xbase = (const char*)xs + (size_t)(b * NCH + ch) * 1605632;
        #pragma unroll
        for (int k2 = 0; k2 < 11; ++k2) {
            if (wv + 4 * k2 < 42) {
                const char* g = (aoff[k2] >= 0) ? (xbase + aoff[k2]) : zb;
                gld16(g, sA + adst[k2]);
            }
        }
    };
    const char* wbase = (const char*)wp + (size_t)yb * ((size_t)NCH * 9 * 16384);
    auto issueB = [&](int flat, int half) {
        const char* gb = wbase + (size_t)flat * 16384 + (wv << 12) + (lane << 4);
        char* db = sB + half * 16384 + (wv << 12);
        #pragma unroll
        for (int j2 = 0; j2 < 4; ++j2)
            gld16(gb + j2 * 1024, db + j2 * 1024);
    };

    f32x16 acc[4][2];
    #pragma unroll
    for (int i = 0; i < 4; ++i)
        #pragma unroll
        for (int j = 0; j < 2; ++j)
            acc[i][j] = (f32x16){0.f,0.f,0.f,0.f,0.f,0.f,0.f,0.f,
                                 0.f,0.f,0.f,0.f,0.f,0.f,0.f,0.f};

    auto mfma_tap = [&](int tap, const char* sBc) {
        const int ky = tap / 3, kx = tap % 3;
        // B frags: [kh][fn][hi/lo], logical quarter q = kh*2 + lk
        short8v Bf[2][2][2];
        #pragma unroll
        for (int kh = 0; kh < 2; ++kh)
            #pragma unroll
            for (int fn = 0; fn < 2; ++fn) {
                int col = ng * 64 + fn * 32 + lcol;
                int off = col * 64 + (((kh * 2 + lk) ^ ((col >> 1) & 3)) << 4);
                Bf[kh][fn][0] = *(const short8v*)(sBc + off);
                Bf[kh][fn][1] = *(const short8v*)(sBc + 8192 + off);
            }
        #pragma unroll
        for (int fm = 0; fm < 4; ++fm) {
            #pragma unroll
            for (int kh = 0; kh < 2; ++kh) {
                int ap = (wvm * 8 + fm * 2 + lyin + ky) * 18 + kx + lx;
                int off = ap * 64 + (((kh * 2 + lk) ^ ((ap >> 1) & 3)) << 4);
                short8v Ah = *(const short8v*)(sA + off);
                short8v Al = *(const short8v*)(sA + 21504 + off);
                // same-acc chains interleaved across the two N-frags
                acc[fm][0] = __builtin_amdgcn_mfma_f32_32x32x16_bf16(Ah, Bf[kh][0][0], acc[fm][0], 0, 0, 0);
                acc[fm][1] = __builtin_amdgcn_mfma_f32_32x32x16_bf16(Ah, Bf[kh][1][0], acc[fm][1], 0, 0, 0);
                acc[fm][0] = __builtin_amdgcn_mfma_f32_32x32x16_bf16(Ah, Bf[kh][0][1], acc[fm][0], 0, 0, 0);
                acc[fm][1] = __builtin_amdgcn_mfma_f32_32x32x16_bf16(Ah, Bf[kh][1][1], acc[fm][1], 0, 0, 0);
                acc[fm][0] = __builtin_amdgcn_mfma_f32_32x32x16_bf16(Al, Bf[kh][0][0], acc[fm][0], 0, 0, 0);
                acc[fm][1] = __builtin_amdgcn_mfma_f32_32x32x16_bf16(Al, Bf[kh][1][0], acc[fm][1], 0, 0, 0);
            }
        }
    };

    // prologue: A(0), B taps {0,1} of chunk 0
    issueA(0);
    issueB(0, 0);
    issueB(1, 1);
    asm volatile("s_waitcnt vmcnt(0)" ::: "memory");
    __syncthreads();

    for (int ch = 0; ch < NCH; ++ch) {
        const int base = ch * 9;
        // 4 tap-pairs: (0,1) (2,3) (4,5) (6,7)
        #pragma unroll
        for (int pe = 0; pe < 4; ++pe) {
            mfma_tap(2 * pe, sB);
            mfma_tap(2 * pe + 1, sB + 16384);
            __syncthreads();                 // done reading both sB halves
            if (pe < 3) {
                issueB(base + 2 * pe + 2, 0);
                issueB(base + 2 * pe + 3, 1);
            } else {
                issueB(base + 8, 0);         // lone tap 8
            }
            asm volatile("s_waitcnt vmcnt(0)" ::: "memory");
            __syncthreads();
        }
        // tap 8 + chunk edge
        mfma_tap(8, sB);
        __syncthreads();                     // done reading sB half0 and sA
        if (ch + 1 < NCH) {
            issueA(ch + 1);
            issueB(base + 9, 0);             // next chunk taps {0,1}
            issueB(base + 10, 1);
        }
        asm volatile("s_waitcnt vmcnt(0)" ::: "memory");
        __syncthreads();
    }

    const float kRS = 1.0f / sqrtf(1.0f + 1e-5f);

    if (!POOL) {
        // write h1s[b][ch2 8][pl2][gy][gx][32] bf16, pixel-swizzled quarters
        // C/D: col = lane&31, row r = (reg&3) + 8*(reg>>2) + 4*lk;
        //      gy = ..fm*2 + (r>>4), gx = .. (r&15)
        unsigned short* h1s = (unsigned short*)out_;
        #pragma unroll
        for (int fm = 0; fm < 4; ++fm) {
            #pragma unroll
            for (int fn = 0; fn < 2; ++fn) {
                int co = yb * 128 + ng * 64 + fn * 32 + lcol;
                float sc = gam[co] * kRS, bi = bet[co];
                int ch2 = co >> 5, sl = co & 31, q = sl >> 3, e = sl & 7;
                size_t base2 = (size_t)(b * 8 + ch2) * 802816;   // u16 per (b,ch2)
                #pragma unroll
                for (int reg = 0; reg < 16; ++reg) {
                    int r = (reg & 3) + 8 * (reg >> 2) + 4 * lk;
                    int gy = ty * 16 + wvm * 8 + fm * 2 + (r >> 4);
                    int gx = tx * 16 + (r & 15);
                    float v = fmaxf(fmaf(acc[fm][fn][reg], sc, bi), 0.f);
                    unsigned int hi, lo;
                    split_bf16(v, hi, lo);
                    int sw = ((18 * gy + gx + 19) >> 1) & 3;
                    size_t po = base2 + ((size_t)gy * 112 + gx) * 32 + (size_t)((q ^ sw) * 8 + e);
                    h1s[po] = (unsigned short)hi;
                    h1s[po + 401408] = (unsigned short)lo;
                }
            }
        }
    } else {
        // fused BN+ReLU + 16x16 avg pool (tile == pool window)
        __syncthreads();                      // all waves past the last barrier
        float* spool = (float*)sA;            // (wv*2+fn) x 32 floats
        #pragma unroll
        for (int fn = 0; fn < 2; ++fn) {
            int co = yb * 128 + ng * 64 + fn * 32 + lcol;
            float sc = gam[co] * kRS, bi = bet[co];
            float s = 0.f;
            #pragma unroll
            for (int fm = 0; fm < 4; ++fm)
                #pragma unroll
                for (int reg = 0; reg < 16; ++reg)
                    s += fmaxf(fmaf(acc[fm][fn][reg], sc, bi), 0.f);
            s += __shfl_xor(s, 32);           // combine lk halves (same co)
            if (lane < 32) spool[(wv * 2 + fn) * 32 + lane] = s;
        }
        __syncthreads();
        if (tid < 128) {
            // tid = ngx*64 + fn*32 + c : co within the yb half
            int ngx = tid >> 6, fn = (tid >> 5) & 1, c = tid & 31;
            float s = spool[(ngx * 2 + fn) * 32 + c] + spool[((2 + ngx) * 2 + fn) * 32 + c];
            float* p1o = (float*)out_;
            p1o[(((size_t)b * 256 + yb * 128 + tid) * 7 + ty) * 7 + tx] = s * (1.f / 256.f);
        }
    }
}

// ---------------- small downstream stages (unchanged) ----------------------

template<int CIN>
__global__ __launch_bounds__(256)
void conv_small_kernel(const float* __restrict__ in, const float* __restrict__ w,
                       const float* __restrict__ gam, const float* __restrict__ bet,
                       float* __restrict__ out, int CO_TOT)
{
    const int co0 = blockIdx.x * 16;
    const int b = blockIdx.y;
    const int tid = threadIdx.x;
    const int px = tid & 63;
    const int wg = tid >> 6;
    const int py = px / 7, pxx = px - py * 7;
    const bool act = px < 49;

    __shared__ float s_in[64][9][9];
    __shared__ float s_w[64][16][9];

    float acc[4] = {0.f, 0.f, 0.f, 0.f};

    for (int ci0 = 0; ci0 < CIN; ci0 += 64) {
        __syncthreads();
        for (int idx = tid; idx < 64 * 81; idx += 256) {
            int ci = idx / 81;
            int rem = idx - ci * 81;
            int r = rem / 9, c = rem - (rem / 9) * 9;
            float v = 0.f;
            if (r >= 1 && r <= 7 && c >= 1 && c <= 7)
                v = in[((size_t)(b * CIN + ci0 + ci) * 7 + (r - 1)) * 7 + (c - 1)];
            s_in[ci][r][c] = v;
        }
        for (int idx = tid; idx < 64 * 16 * 9; idx += 256) {
            int co = idx / 576;
            int rem = idx - co * 576;
            int ci = rem / 9, tap = rem - (rem / 9) * 9;
            s_w[ci][co][tap] = w[((size_t)(co0 + co) * CIN + ci0 + ci) * 9 + tap];
        }
        __syncthreads();
        if (act) {
            for (int ci = 0; ci < 64; ++ci) {
                #pragma unroll
                for (int ky = 0; ky < 3; ++ky)
                    #pragma unroll
                    for (int kx = 0; kx < 3; ++kx) {
                        float v = s_in[ci][py + ky][pxx + kx];
                        #pragma unroll
                        for (int j = 0; j < 4; ++j)
                            acc[j] = fmaf(v, s_w[ci][wg * 4 + j][ky * 3 + kx], acc[j]);
                    }
            }
        }
    }
    if (act) {
        const float kRS = 1.0f / sqrtf(1.0f + 1e-5f);
        #pragma unroll
        for (int j = 0; j < 4; ++j) {
            int cog = co0 + wg * 4 + j;
            float v = fmaxf(fmaf(acc[j], gam[cog] * kRS, bet[cog]), 0.f);
            out[(size_t)(b * CO_TOT + cog) * 49 + py * 7 + pxx] = v;
        }
    }
}

__global__ void pool3x3_kernel(const float* __restrict__ in, float* __restrict__ out)
{
    int o = blockIdx.x * 256 + threadIdx.x;
    if (o >= 16 * 128 * 9) return;
    int xo = o % 3;
    int yo = (o / 3) % 3;
    int bc = o / 9;
    const float* p = in + (size_t)bc * 49;
    float s = 0.f;
    #pragma unroll
    for (int ky = 0; ky < 3; ++ky)
        #pragma unroll
        for (int kx = 0; kx < 3; ++kx)
            s += p[(yo * 2 + ky) * 7 + xo * 2 + kx];
    out[o] = s * (1.0f / 9.0f);
}

__global__ __launch_bounds__(256)
void conv5_kernel(const float* __restrict__ in, const float* __restrict__ w,
                  const float* __restrict__ gam, const float* __restrict__ bet,
                  float* __restrict__ out)
{
    const int co0 = blockIdx.x * 16;
    const int b = blockIdx.y;
    const int tid = threadIdx.x;
    __shared__ float s_in[128][5][5];
    __shared__ float s_w[64][16][9];

    for (int idx = tid; idx < 128 * 25; idx += 256) {
        int ci = idx / 25;
        int rem = idx - ci * 25;
        int r = rem / 5, c = rem - (rem / 5) * 5;
        float v = 0.f;
        if (r >= 1 && r <= 3 && c >= 1 && c <= 3)
            v = in[((size_t)(b * 128 + ci) * 3 + (r - 1)) * 3 + (c - 1)];
        s_in[ci][r][c] = v;
    }

    float acc = 0.f;
    const int co = tid / 9;
    const int px = tid - co * 9;
    const int pyy = px / 3, pxx = px - pyy * 3;
    const bool act = tid < 144;

    for (int ci0 = 0; ci0 < 128; ci0 += 64) {
        __syncthreads();
        for (int idx = tid; idx < 64 * 16 * 9; idx += 256) {
            int c2 = idx / 576;
            int rem = idx - c2 * 576;
            int ci = rem / 9, tap = rem - (rem / 9) * 9;
            s_w[ci][c2][tap] = w[((size_t)(co0 + c2) * 128 + ci0 + ci) * 9 + tap];
        }
        __syncthreads();
        if (act) {
            for (int ci = 0; ci < 64; ++ci) {
                #pragma unroll
                for (int ky = 0; ky < 3; ++ky)
                    #pragma unroll
                    for (int kx = 0; kx < 3; ++kx)
                        acc = fmaf(s_in[ci0 + ci][pyy + ky][pxx + kx],
                                   s_w[ci][co][ky * 3 + kx], acc);
            }
        }
    }
    if (act) {
        const float kRS = 1.0f / sqrtf(1.0f + 1e-5f);
        int cog = co0 + co;
        out[(size_t)(b * 64 + cog) * 9 + px] =
            fmaxf(fmaf(acc, gam[cog] * kRS, bet[cog]), 0.f);
    }
}

__global__ void fc_kernel(const float* __restrict__ h5, const float* __restrict__ wfc,
                          float* __restrict__ feats)
{
    int o = blockIdx.x * 256 + threadIdx.x;
    if (o >= 16 * 128) return;
    int b = o >> 7, j = o & 127;
    const float* hp = h5 + b * 576;
    const float* wp = wfc + j * 576;
    float s = 0.f;
    for (int k = 0; k < 576; ++k) s = fmaf(hp[k], wp[k], s);
    feats[o] = s;
}

__global__ __launch_bounds__(256)
void attn_kernel(const float* __restrict__ feats, const float* __restrict__ mixw,
                 float* __restrict__ out)
{
    const int bo = blockIdx.x;
    const int b = bo >> 3, o = bo & 7;
    const int tid = threadIdx.x;
    __shared__ float s_att[4][3136];
    __shared__ float s_red[4];

    float mv[4];
    float mmax = -1e30f;
    #pragma unroll
    for (int g = 0; g < 4; ++g) { mv[g] = mixw[o * 4 + g]; mmax = fmaxf(mmax, mv[g]); }
    float msum = 0.f;
    #pragma unroll
    for (int g = 0; g < 4; ++g) { mv[g] = expf(mv[g] - mmax); msum += mv[g]; }
    #pragma unroll
    for (int g = 0; g < 4; ++g) mv[g] /= msum;

    const float LOG_R = 1.0986122886681098f;
    float winv[4];
    for (int g = 0; g < 4; ++g) {
        float f0 = feats[b * 128 + o * 16 + g * 4 + 0];
        float f1 = feats[b * 128 + o * 16 + g * 4 + 1];
        float f2 = feats[b * 128 + o * 16 + g * 4 + 2];
        float f3 = feats[b * 128 + o * 16 + g * 4 + 3];
        float m_x = 55.f / (1.f + expf(-f0));
        float m_y = 55.f / (1.f + expf(-f1));
        float r = expf((2.f / (1.f + expf(-f2)) - 1.f) * LOG_R);
        float rho = 1.6f / (1.f + expf(-f3)) - 0.8f;
        float denom = (-0.5f / (1.f - rho * rho)) * (1.f / 3136.f);
        float rin = 1.f / r;

        float ssum = 0.f;
        for (int p = tid; p < 3136; p += 256) {
            int i = p / 56;
            int j = p - i * 56;
            float dx = m_x - (float)i;
            float dy = m_y - (float)j;
            float quad = dx * dx * r + dy * dy * rin - 2.f * rho * dx * dy;
            float e = expf(denom * quad);
            s_att[g][p] = e;
            ssum += e;
        }
        #pragma unroll
        for (int off = 32; off > 0; off >>= 1) ssum += __shfl_down(ssum, off);
        if ((tid & 63) == 0) s_red[tid >> 6] = ssum;
        __syncthreads();
        winv[g] = mv[g] / (s_red[0] + s_red[1] + s_red[2] + s_red[3]);
        __syncthreads();
    }

    for (int p = tid; p < 3136; p += 256) {
        float v = 0.f;
        #pragma unroll
        for (int g = 0; g < 4; ++g) v += s_att[g][p] * winv[g];
        out[(size_t)bo * 3136 + p] = v;
    }
}

// ---------------------------------------------------------------------------

extern "C" void kernel_launch(void* const* d_in, const int* in_sizes, int n_in,
                              void* d_out, int out_size, void* d_ws, size_t ws_size,
                              hipStream_t stream)
{
    const float* x    = (const float*)d_in[0];
    const float* w1   = (const float*)d_in[1];
    const float* g1   = (const float*)d_in[2];
    const float* b1   = (const float*)d_in[3];
    const float* w2   = (const float*)d_in[4];
    const float* g2   = (const float*)d_in[5];
    const float* b2   = (const float*)d_in[6];
    const float* w3   = (const float*)d_in[7];
    const float* g3   = (const float*)d_in[8];
    const float* b3   = (const float*)d_in[9];
    const float* w4   = (const float*)d_in[10];
    const float* g4   = (const float*)d_in[11];
    const float* b4   = (const float*)d_in[12];
    const float* w5   = (const float*)d_in[13];
    const float* g5   = (const float*)d_in[14];
    const float* b5   = (const float*)d_in[15];
    const float* wfc  = (const float*)d_in[16];
    const float* mixw = (const float*)d_in[17];
    float* outp = (float*)d_out;

    // dynamic-LDS opt-in (immediate host call, deterministic, capture-safe)
    hipFuncSetAttribute(reinterpret_cast<const void*>(&conv_mfma_kernel<512, false>),
                        hipFuncAttributeMaxDynamicSharedMemorySize, 75776);
    hipFuncSetAttribute(reinterpret_cast<const void*>(&conv_mfma_kernel<256, true>),
                        hipFuncAttributeMaxDynamicSharedMemorySize, 75776);

    // workspace layout (bytes)
    char* wsb = (char*)d_ws;
    unsigned short* wp = (unsigned short*)wsb;   wsb += (size_t)2359296 * 2;      // 4.7MB (reused)
    unsigned short* xs = (unsigned short*)wsb;   wsb += (size_t)16*16*2*12544*32*2;  // 411MB
    unsigned short* h1s = (unsigned short*)wsb;  wsb += (size_t)16*8*2*12544*32*2;   // 205.5MB
    float* p1 = (float*)wsb;  wsb += 200704 * 4;
    float* h3 = (float*)wsb;  wsb += 100352 * 4;
    float* h4 = (float*)wsb;  wsb += 100352 * 4;
    float* p2 = (float*)wsb;  wsb += 18432 * 4;
    float* h5 = (float*)wsb;  wsb += 9216 * 4;
    float* fts = (float*)wsb; wsb += 2048 * 4;
    float* zerob = (float*)wsb; wsb += 64 * 4;

    zero_kernel<<<1, 64, 0, stream>>>(zerob);
    presplit_x_kernel<<<dim3(112, 16, 16), 256, 0, stream>>>(x, xs);

    prep_w_kernel<<<9216, 256, 0, stream>>>(w1, wp, 512);
    conv_mfma_kernel<512, false><<<dim3(49, 2, 16), 256, 75776, stream>>>(xs, wp, g1, b1, h1s, zerob);

    prep_w_kernel<<<4608, 256, 0, stream>>>(w2, wp, 256);
    conv_mfma_kernel<256, true><<<dim3(49, 2, 16), 256, 75776, stream>>>(h1s, wp, g2, b2, p1, zerob);

    conv_small_kernel<256><<<dim3(8, 16), 256, 0, stream>>>(p1, w3, g3, b3, h3, 128);
    conv_small_kernel<128><<<dim3(8, 16), 256, 0, stream>>>(h3, w4, g4, b4, h4, 128);

    pool3x3_kernel<<<72, 256, 0, stream>>>(h4, p2);
    conv5_kernel<<<dim3(4, 16), 256, 0, stream>>>(p2, w5, g5, b5, h5);
    fc_kernel<<<8, 256, 0, stream>>>(h5, wfc, fts);
    attn_kernel<<<128, 256, 0, stream>>>(fts, mixw, outp);
}

// Round 12
// 1829.060 us; speedup vs baseline: 3.4651x; 1.2223x over previous
//
#include <hip/hip_runtime.h>
#include <math.h>

// ---------------------------------------------------------------------------
// BivariateNormalAttention pipeline.
// Round 11: R7 conv structure EXACTLY (2 independent 4-wave blocks/CU, 2-tap
//   B staging, 16x16x32 MFMA, verified conflict-free swizzles) with a
//   numerics-driven work reduction in conv2:
//   - conv1: exact 3-product (AhBh+AhBl+AlBh), h1 stored as RNE-bf16 HI ONLY
//     (lo plane never written: conv1 WRITE halves).
//   - conv2: 2-product (AhBh+AhBl) — drops the A-residual term; error is
//     h1's unbiased RNE quantization (~2^-10 rms), attenuated by the 16x16
//     pool -> ~1e-6 on output (margin: absmax 3.8e-6 vs thr 11.9e-6).
//     A staged hi-plane-only: sA 21.5KB, A-reads/tap halve (16->8),
//     MFMA/tap 96->64.
//   - fc parallelized (512 blocks, lane-split K + shuffle reduce).
// ---------------------------------------------------------------------------

typedef __attribute__((ext_vector_type(8))) short short8v;
typedef __attribute__((ext_vector_type(4))) float f32x4;

__device__ __forceinline__ void split_bf16(float f, unsigned int& hi, unsigned int& lo)
{
    unsigned int u = __float_as_uint(f);
    hi = u >> 16;                                    // truncated bf16 hi
    float hif = __uint_as_float(u & 0xffff0000u);
    lo = __float_as_uint(f - hif) >> 16;             // residual, truncated
}

__device__ __forceinline__ void gld16(const void* g, void* l)
{
    __builtin_amdgcn_global_load_lds(
        (const __attribute__((address_space(1))) unsigned int*)g,
        (__attribute__((address_space(3))) unsigned int*)l, 16, 0, 0);
}

__global__ void zero_kernel(float* z) { z[threadIdx.x] = 0.f; }

// wp[y2][ch][tap][pl2][co128][k32] u16; within each co's 64B row the 16B
// quarters are pre-swizzled: phys quarter qp holds logical q = qp ^ ((co>>1)&3).
__global__ __launch_bounds__(256)
void prep_w_kernel(const float* __restrict__ w, unsigned short* __restrict__ wp, int CIN)
{
    int idx = blockIdx.x * 256 + threadIdx.x;
    int NCH = CIN >> 5;
    int total = 2 * NCH * 9 * 2 * 128 * 32;
    if (idx >= total) return;
    int kk = idx & 31;
    int co = (idx >> 5) & 127;
    int pl = (idx >> 12) & 1;
    int rest = idx >> 13;            // (y*NCH + ch)*9 + tap
    int tap = rest % 9;
    rest /= 9;
    int ch = rest % NCH;
    int y = rest / NCH;
    int qp = kk >> 3, e = kk & 7;
    int q = qp ^ ((co >> 1) & 3);
    int ci = ch * 32 + q * 8 + e;
    int cog = y * 128 + co;
    float f = w[((size_t)cog * CIN + ci) * 9 + tap];
    unsigned int hi, lo;
    split_bf16(f, hi, lo);
    wp[idx] = (unsigned short)(pl ? lo : hi);
}

// x[b][512][112][112] f32 -> xs[b][16ch][2pl][112][112][32ci] bf16,
// quarters pre-swizzled by pixel: qp = q ^ ((18*gy+gx+19)>>1 & 3)
__global__ __launch_bounds__(256)
void presplit_x_kernel(const float* __restrict__ x, unsigned short* __restrict__ xs)
{
    const int gy = blockIdx.x, ch = blockIdx.y, b = blockIdx.z;
    const int tid = threadIdx.x;
    __shared__ float s[32][113];
    for (int i = tid; i < 32 * 112; i += 256) {
        int ci = i / 112, xx = i - ci * 112;
        s[ci][xx] = x[(((size_t)(b * 16 + ch) * 32 + ci) * 112 + gy) * 112 + xx];
    }
    __syncthreads();
    unsigned int* oh = (unsigned int*)(xs + ((size_t)(b * 16 + ch) * 2 * 12544 + (size_t)gy * 112) * 32);
    unsigned int* ol = oh + 12544 * 16;   // plane stride in u32: 12544*32/2
    for (int i = tid; i < 112 * 16; i += 256) {
        int px = i >> 4, t = i & 15;          // t = u32 slot within 64B row
        int qp = t >> 2, ep = t & 3;
        int sw = ((18 * gy + px + 19) >> 1) & 3;
        int q = qp ^ sw;
        int ci0 = q * 8 + ep * 2;
        float f0 = s[ci0][px], f1 = s[ci0 + 1][px];
        unsigned int h0, l0, h1, l1;
        split_bf16(f0, h0, l0);
        split_bf16(f1, h1, l1);
        oh[(size_t)px * 16 + t] = h0 | (h1 << 16);
        ol[(size_t)px * 16 + t] = l0 | (l1 << 16);
    }
}

// POOL=false: conv1 (3-product, xs hi+lo) -> h1s hi-only RNE bf16.
// POOL=true : conv2 (2-product, h1s hi only) -> pooled fp32 [B,256,7,7].
template<int CIN, bool POOL>
__global__ __launch_bounds__(256, 2)
void conv_mfma_kernel(const unsigned short* __restrict__ xs,
                      const unsigned short* __restrict__ wp,
                      const float* __restrict__ gam, const float* __restrict__ bet,
                      void* __restrict__ out_, const float* __restrict__ zerob)
{
    constexpr int NCH = CIN >> 5;
    constexpr int APL = POOL ? 1 : 2;          // A planes staged
    constexpr int AJ = 21 * APL;               // 1KB slices per chunk
    constexpr int AISS = (AJ + 3) / 4;         // per-wave issue slots
    constexpr size_t XSTR = (size_t)802816 * APL;  // bytes per (b,chunk)
    extern __shared__ __align__(16) char smem[];   // conv1 75776, conv2 54272
    char* sA = smem;                 // APL x 21504: [pl][336px][64B] (324 used)
    char* sB = smem + APL * 21504;   // 2 x 16384: [half][pl2][co128][64B]

    const int tid = threadIdx.x;
    const int lane = tid & 63;
    const int wv = tid >> 6;
    const int wvm = wv >> 1, ng = wv & 1;
    const int m = lane & 15, kg = lane >> 4;
    const int ty = blockIdx.x / 7, tx = blockIdx.x % 7;
    const int yb = blockIdx.y;
    const int b = blockIdx.z;

    // ---- A staging geometry: AJ wave-issues of 1KB, round-robin over 4 waves
    int aoff[AISS];
    unsigned adst[AISS];
    #pragma unroll
    for (int k2 = 0; k2 < AISS; ++k2) {
        int j = wv + 4 * k2;
        aoff[k2] = -1; adst[k2] = 0;
        if (j < AJ) {
            int pl = j / 21, jj = j - pl * 21;
            int px = jj * 16 + (lane >> 2);
            int py = px / 18, pxx = px - py * 18;
            int gy = ty * 16 + py - 1, gx = tx * 16 + pxx - 1;
            bool valid = (px < 324) && ((unsigned)gy < 112u) && ((unsigned)gx < 112u);
            aoff[k2] = valid ? (pl * 802816 + ((gy * 112 + gx) << 6) + ((lane & 3) << 4)) : -1;
            adst[k2] = pl * 21504 + jj * 1024;
        }
    }
    const char* zb = (const char*)zerob + ((lane & 3) << 4);

    auto issueA = [&](int ch) {
        const char* xbase = (const char*)xs + (size_t)(b * NCH + ch) * XSTR;
        #pragma unroll
        for (int k2 = 0; k2 < AISS; ++k2) {
            if (wv + 4 * k2 < AJ) {
                const char* g = (aoff[k2] >= 0) ? (xbase + aoff[k2]) : zb;
                gld16(g, sA + adst[k2]);
            }
        }
    };
    const char* wbase = (const char*)wp + (size_t)yb * ((size_t)NCH * 9 * 16384);
    auto issueB = [&](int flat, int half) {
        const char* gb = wbase + (size_t)flat * 16384 + (wv << 12) + (lane << 4);
        char* db = sB + half * 16384 + (wv << 12);
        #pragma unroll
        for (int j2 = 0; j2 < 4; ++j2)
            gld16(gb + j2 * 1024, db + j2 * 1024);
    };

    f32x4 acc[8][4];
    #pragma unroll
    for (int i = 0; i < 8; ++i)
        #pragma unroll
        for (int j = 0; j < 4; ++j)
            acc[i][j] = (f32x4){0.f, 0.f, 0.f, 0.f};

    auto mfma_tap = [&](int tap, const char* sBc) {
        const int ky = tap / 3, kx = tap % 3;
        short8v Bh_[4], Bl_[4];
        #pragma unroll
        for (int nf = 0; nf < 4; ++nf) {
            int col = ng * 64 + nf * 16 + m;
            int off = col * 64 + ((kg ^ ((col >> 1) & 3)) << 4);
            Bh_[nf] = *(const short8v*)(sBc + off);
            Bl_[nf] = *(const short8v*)(sBc + 8192 + off);
        }
        #pragma unroll
        for (int mf = 0; mf < 8; ++mf) {
            int ap = (wvm * 8 + mf + ky) * 18 + kx + m;
            int off = ap * 64 + ((kg ^ ((ap >> 1) & 3)) << 4);
            short8v Ah = *(const short8v*)(sA + off);
            if constexpr (!POOL) {
                short8v Al = *(const short8v*)(sA + 21504 + off);
                #pragma unroll
                for (int nf = 0; nf < 4; ++nf) {
                    acc[mf][nf] = __builtin_amdgcn_mfma_f32_16x16x32_bf16(Ah, Bh_[nf], acc[mf][nf], 0, 0, 0);
                    acc[mf][nf] = __builtin_amdgcn_mfma_f32_16x16x32_bf16(Ah, Bl_[nf], acc[mf][nf], 0, 0, 0);
                    acc[mf][nf] = __builtin_amdgcn_mfma_f32_16x16x32_bf16(Al, Bh_[nf], acc[mf][nf], 0, 0, 0);
                }
            } else {
                #pragma unroll
                for (int nf = 0; nf < 4; ++nf) {
                    acc[mf][nf] = __builtin_amdgcn_mfma_f32_16x16x32_bf16(Ah, Bh_[nf], acc[mf][nf], 0, 0, 0);
                    acc[mf][nf] = __builtin_amdgcn_mfma_f32_16x16x32_bf16(Ah, Bl_[nf], acc[mf][nf], 0, 0, 0);
                }
            }
        }
    };

    // prologue: A(0), B taps {0,1} of chunk 0
    issueA(0);
    issueB(0, 0);
    issueB(1, 1);
    asm volatile("s_waitcnt vmcnt(0)" ::: "memory");
    __syncthreads();

    for (int ch = 0; ch < NCH; ++ch) {
        const int base = ch * 9;
        // 4 tap-pairs: (0,1) (2,3) (4,5) (6,7)
        #pragma unroll
        for (int pe = 0; pe < 4; ++pe) {
            mfma_tap(2 * pe, sB);
            mfma_tap(2 * pe + 1, sB + 16384);
            __syncthreads();                 // done reading both sB halves
            if (pe < 3) {
                issueB(base + 2 * pe + 2, 0);
                issueB(base + 2 * pe + 3, 1);
            } else {
                issueB(base + 8, 0);         // lone tap 8
            }
            asm volatile("s_waitcnt vmcnt(0)" ::: "memory");
            __syncthreads();
        }
        // tap 8 + chunk edge
        mfma_tap(8, sB);
        __syncthreads();                     // done reading sB half0 and sA
        if (ch + 1 < NCH) {
            issueA(ch + 1);
            issueB(base + 9, 0);             // next chunk taps {0,1}
            issueB(base + 10, 1);
        }
        asm volatile("s_waitcnt vmcnt(0)" ::: "memory");
        __syncthreads();
    }

    const float kRS = 1.0f / sqrtf(1.0f + 1e-5f);

    if (!POOL) {
        // write h1s[b][ch2 8][gy][gx][32] bf16 HI ONLY (RNE), swizzled quarters
        unsigned short* h1s = (unsigned short*)out_;
        #pragma unroll
        for (int mf = 0; mf < 8; ++mf) {
            int gy = ty * 16 + wvm * 8 + mf;
            #pragma unroll
            for (int nf = 0; nf < 4; ++nf) {
                int co = yb * 128 + ng * 64 + nf * 16 + m;
                float sc = gam[co] * kRS, bi = bet[co];
                int ch2 = co >> 5, sl = co & 31, q = sl >> 3, e = sl & 7;
                size_t base2 = (size_t)(b * 8 + ch2) * 401408;   // u16 per (b,ch2)
                #pragma unroll
                for (int r = 0; r < 4; ++r) {
                    int gx = tx * 16 + kg * 4 + r;
                    float v = fmaxf(fmaf(acc[mf][nf][r], sc, bi), 0.f);
                    unsigned int u = __float_as_uint(v);
                    u += 0x7fffu + ((u >> 16) & 1u);             // RNE to bf16
                    int sw = ((18 * gy + gx + 19) >> 1) & 3;
                    size_t po = base2 + ((size_t)gy * 112 + gx) * 32 + (size_t)((q ^ sw) * 8 + e);
                    h1s[po] = (unsigned short)(u >> 16);
                }
            }
        }
    } else {
        // fused BN+ReLU + 16x16 avg pool (tile == pool window)
        __syncthreads();                      // all waves past the last barrier
        float* spool = (float*)smem;          // 4 waves x 4 nf x 16 co floats
        #pragma unroll
        for (int nf = 0; nf < 4; ++nf) {
            int co = yb * 128 + ng * 64 + nf * 16 + m;
            float sc = gam[co] * kRS, bi = bet[co];
            float s = 0.f;
            #pragma unroll
            for (int mf = 0; mf < 8; ++mf)
                #pragma unroll
                for (int r = 0; r < 4; ++r)
                    s += fmaxf(fmaf(acc[mf][nf][r], sc, bi), 0.f);
            s += __shfl_xor(s, 16);
            s += __shfl_xor(s, 32);
            if (lane < 16) spool[(wv * 4 + nf) * 16 + lane] = s;
        }
        __syncthreads();
        if (tid < 128) {
            // tid = ngx*64 + nf*16 + m : co within the yb half
            int ngx = tid >> 6, rem = tid & 63;
            int nf = rem >> 4, mm = rem & 15;
            float s = spool[(ngx * 4 + nf) * 16 + mm] + spool[((2 + ngx) * 4 + nf) * 16 + mm];
            float* p1o = (float*)out_;
            p1o[(((size_t)b * 256 + yb * 128 + tid) * 7 + ty) * 7 + tx] = s * (1.f / 256.f);
        }
    }
}

// ---------------- small downstream stages ----------------------------------

template<int CIN>
__global__ __launch_bounds__(256)
void conv_small_kernel(const float* __restrict__ in, const float* __restrict__ w,
                       const float* __restrict__ gam, const float* __restrict__ bet,
                       float* __restrict__ out, int CO_TOT)
{
    const int co0 = blockIdx.x * 16;
    const int b = blockIdx.y;
    const int tid = threadIdx.x;
    const int px = tid & 63;
    const int wg = tid >> 6;
    const int py = px / 7, pxx = px - py * 7;
    const bool act = px < 49;

    __shared__ float s_in[64][9][9];
    __shared__ float s_w[64][16][9];

    float acc[4] = {0.f, 0.f, 0.f, 0.f};

    for (int ci0 = 0; ci0 < CIN; ci0 += 64) {
        __syncthreads();
        for (int idx = tid; idx < 64 * 81; idx += 256) {
            int ci = idx / 81;
            int rem = idx - ci * 81;
            int r = rem / 9, c = rem - (rem / 9) * 9;
            float v = 0.f;
            if (r >= 1 && r <= 7 && c >= 1 && c <= 7)
                v = in[((size_t)(b * CIN + ci0 + ci) * 7 + (r - 1)) * 7 + (c - 1)];
            s_in[ci][r][c] = v;
        }
        for (int idx = tid; idx < 64 * 16 * 9; idx += 256) {
            int co = idx / 576;
            int rem = idx - co * 576;
            int ci = rem / 9, tap = rem - (rem / 9) * 9;
            s_w[ci][co][tap] = w[((size_t)(co0 + co) * CIN + ci0 + ci) * 9 + tap];
        }
        __syncthreads();
        if (act) {
            for (int ci = 0; ci < 64; ++ci) {
                #pragma unroll
                for (int ky = 0; ky < 3; ++ky)
                    #pragma unroll
                    for (int kx = 0; kx < 3; ++kx) {
                        float v = s_in[ci][py + ky][pxx + kx];
                        #pragma unroll
                        for (int j = 0; j < 4; ++j)
                            acc[j] = fmaf(v, s_w[ci][wg * 4 + j][ky * 3 + kx], acc[j]);
                    }
            }
        }
    }
    if (act) {
        const float kRS = 1.0f / sqrtf(1.0f + 1e-5f);
        #pragma unroll
        for (int j = 0; j < 4; ++j) {
            int cog = co0 + wg * 4 + j;
            float v = fmaxf(fmaf(acc[j], gam[cog] * kRS, bet[cog]), 0.f);
            out[(size_t)(b * CO_TOT + cog) * 49 + py * 7 + pxx] = v;
        }
    }
}

__global__ void pool3x3_kernel(const float* __restrict__ in, float* __restrict__ out)
{
    int o = blockIdx.x * 256 + threadIdx.x;
    if (o >= 16 * 128 * 9) return;
    int xo = o % 3;
    int yo = (o / 3) % 3;
    int bc = o / 9;
    const float* p = in + (size_t)bc * 49;
    float s = 0.f;
    #pragma unroll
    for (int ky = 0; ky < 3; ++ky)
        #pragma unroll
        for (int kx = 0; kx < 3; ++kx)
            s += p[(yo * 2 + ky) * 7 + xo * 2 + kx];
    out[o] = s * (1.0f / 9.0f);
}

__global__ __launch_bounds__(256)
void conv5_kernel(const float* __restrict__ in, const float* __restrict__ w,
                  const float* __restrict__ gam, const float* __restrict__ bet,
                  float* __restrict__ out)
{
    const int co0 = blockIdx.x * 16;
    const int b = blockIdx.y;
    const int tid = threadIdx.x;
    __shared__ float s_in[128][5][5];
    __shared__ float s_w[64][16][9];

    for (int idx = tid; idx < 128 * 25; idx += 256) {
        int ci = idx / 25;
        int rem = idx - ci * 25;
        int r = rem / 5, c = rem - (rem / 5) * 5;
        float v = 0.f;
        if (r >= 1 && r <= 3 && c >= 1 && c <= 3)
            v = in[((size_t)(b * 128 + ci) * 3 + (r - 1)) * 3 + (c - 1)];
        s_in[ci][r][c] = v;
    }

    float acc = 0.f;
    const int co = tid / 9;
    const int px = tid - co * 9;
    const int pyy = px / 3, pxx = px - pyy * 3;
    const bool act = tid < 144;

    for (int ci0 = 0; ci0 < 128; ci0 += 64) {
        __syncthreads();
        for (int idx = tid; idx < 64 * 16 * 9; idx += 256) {
            int c2 = idx / 576;
            int rem = idx - c2 * 576;
            int ci = rem / 9, tap = rem - (rem / 9) * 9;
            s_w[ci][c2][tap] = w[((size_t)(co0 + c2) * 128 + ci0 + ci) * 9 + tap];
        }
        __syncthreads();
        if (act) {
            for (int ci = 0; ci < 64; ++ci) {
                #pragma unroll
                for (int ky = 0; ky < 3; ++ky)
                    #pragma unroll
                    for (int kx = 0; kx < 3; ++kx)
                        acc = fmaf(s_in[ci0 + ci][pyy + ky][pxx + kx],
                                   s_w[ci][co][ky * 3 + kx], acc);
            }
        }
    }
    if (act) {
        const float kRS = 1.0f / sqrtf(1.0f + 1e-5f);
        int cog = co0 + co;
        out[(size_t)(b * 64 + cog) * 9 + px] =
            fmaxf(fmaf(acc, gam[cog] * kRS, bet[cog]), 0.f);
    }
}

// fc: 512 blocks x 256 threads; 4 outputs/block, 64 lanes per output.
__global__ __launch_bounds__(256)
void fc_kernel(const float* __restrict__ h5, const float* __restrict__ wfc,
               float* __restrict__ feats)
{
    int o = blockIdx.x * 4 + (threadIdx.x >> 6);
    int lane = threadIdx.x & 63;
    int b = o >> 7, j = o & 127;
    const float* hp = h5 + b * 576;
    const float* wp = wfc + j * 576;
    float s = 0.f;
    for (int k = lane; k < 576; k += 64) s = fmaf(hp[k], wp[k], s);
    #pragma unroll
    for (int off = 32; off > 0; off >>= 1) s += __shfl_down(s, off);
    if (lane == 0) feats[o] = s;
}

__global__ __launch_bounds__(256)
void attn_kernel(const float* __restrict__ feats, const float* __restrict__ mixw,
                 float* __restrict__ out)
{
    const int bo = blockIdx.x;
    const int b = bo >> 3, o = bo & 7;
    const int tid = threadIdx.x;
    __shared__ float s_att[4][3136];
    __shared__ float s_red[4];

    float mv[4];
    float mmax = -1e30f;
    #pragma unroll
    for (int g = 0; g < 4; ++g) { mv[g] = mixw[o * 4 + g]; mmax = fmaxf(mmax, mv[g]); }
    float msum = 0.f;
    #pragma unroll
    for (int g = 0; g < 4; ++g) { mv[g] = expf(mv[g] - mmax); msum += mv[g]; }
    #pragma unroll
    for (int g = 0; g < 4; ++g) mv[g] /= msum;

    const float LOG_R = 1.0986122886681098f;
    float winv[4];
    for (int g = 0; g < 4; ++g) {
        float f0 = feats[b * 128 + o * 16 + g * 4 + 0];
        float f1 = feats[b * 128 + o * 16 + g * 4 + 1];
        float f2 = feats[b * 128 + o * 16 + g * 4 + 2];
        float f3 = feats[b * 128 + o * 16 + g * 4 + 3];
        float m_x = 55.f / (1.f + expf(-f0));
        float m_y = 55.f / (1.f + expf(-f1));
        float r = expf((2.f / (1.f + expf(-f2)) - 1.f) * LOG_R);
        float rho = 1.6f / (1.f + expf(-f3)) - 0.8f;
        float denom = (-0.5f / (1.f - rho * rho)) * (1.f / 3136.f);
        float rin = 1.f / r;

        float ssum = 0.f;
        for (int p = tid; p < 3136; p += 256) {
            int i = p / 56;
            int j = p - i * 56;
            float dx = m_x - (float)i;
            float dy = m_y - (float)j;
            float quad = dx * dx * r + dy * dy * rin - 2.f * rho * dx * dy;
            float e = expf(denom * quad);
            s_att[g][p] = e;
            ssum += e;
        }
        #pragma unroll
        for (int off = 32; off > 0; off >>= 1) ssum += __shfl_down(ssum, off);
        if ((tid & 63) == 0) s_red[tid >> 6] = ssum;
        __syncthreads();
        winv[g] = mv[g] / (s_red[0] + s_red[1] + s_red[2] + s_red[3]);
        __syncthreads();
    }

    for (int p = tid; p < 3136; p += 256) {
        float v = 0.f;
        #pragma unroll
        for (int g = 0; g < 4; ++g) v += s_att[g][p] * winv[g];
        out[(size_t)bo * 3136 + p] = v;
    }
}

// ---------------------------------------------------------------------------

extern "C" void kernel_launch(void* const* d_in, const int* in_sizes, int n_in,
                              void* d_out, int out_size, void* d_ws, size_t ws_size,
                              hipStream_t stream)
{
    const float* x    = (const float*)d_in[0];
    const float* w1   = (const float*)d_in[1];
    const float* g1   = (const float*)d_in[2];
    const float* b1   = (const float*)d_in[3];
    const float* w2   = (const float*)d_in[4];
    const float* g2   = (const float*)d_in[5];
    const float* b2   = (const float*)d_in[6];
    const float* w3   = (const float*)d_in[7];
    const float* g3   = (const float*)d_in[8];
    const float* b3   = (const float*)d_in[9];
    const float* w4   = (const float*)d_in[10];
    const float* g4   = (const float*)d_in[11];
    const float* b4   = (const float*)d_in[12];
    const float* w5   = (const float*)d_in[13];
    const float* g5   = (const float*)d_in[14];
    const float* b5   = (const float*)d_in[15];
    const float* wfc  = (const float*)d_in[16];
    const float* mixw = (const float*)d_in[17];
    float* outp = (float*)d_out;

    // dynamic-LDS opt-in (immediate host call, deterministic, capture-safe)
    hipFuncSetAttribute(reinterpret_cast<const void*>(&conv_mfma_kernel<512, false>),
                        hipFuncAttributeMaxDynamicSharedMemorySize, 75776);
    hipFuncSetAttribute(reinterpret_cast<const void*>(&conv_mfma_kernel<256, true>),
                        hipFuncAttributeMaxDynamicSharedMemorySize, 54272);

    // workspace layout (bytes)
    char* wsb = (char*)d_ws;
    unsigned short* wp = (unsigned short*)wsb;   wsb += (size_t)2359296 * 2;      // 4.7MB (reused)
    unsigned short* xs = (unsigned short*)wsb;   wsb += (size_t)16*16*2*12544*32*2;  // 411MB
    unsigned short* h1s = (unsigned short*)wsb;  wsb += (size_t)16*8*12544*32*2;     // 102.8MB (hi only)
    float* p1 = (float*)wsb;  wsb += 200704 * 4;
    float* h3 = (float*)wsb;  wsb += 100352 * 4;
    float* h4 = (float*)wsb;  wsb += 100352 * 4;
    float* p2 = (float*)wsb;  wsb += 18432 * 4;
    float* h5 = (float*)wsb;  wsb += 9216 * 4;
    float* fts = (float*)wsb; wsb += 2048 * 4;
    float* zerob = (float*)wsb; wsb += 64 * 4;

    zero_kernel<<<1, 64, 0, stream>>>(zerob);
    presplit_x_kernel<<<dim3(112, 16, 16), 256, 0, stream>>>(x, xs);

    prep_w_kernel<<<9216, 256, 0, stream>>>(w1, wp, 512);
    conv_mfma_kernel<512, false><<<dim3(49, 2, 16), 256, 75776, stream>>>(xs, wp, g1, b1, h1s, zerob);

    prep_w_kernel<<<4608, 256, 0, stream>>>(w2, wp, 256);
    conv_mfma_kernel<256, true><<<dim3(49, 2, 16), 256, 54272, stream>>>(h1s, wp, g2, b2, p1, zerob);

    conv_small_kernel<256><<<dim3(8, 16), 256, 0, stream>>>(p1, w3, g3, b3, h3, 128);
    conv_small_kernel<128><<<dim3(8, 16), 256, 0, stream>>>(h3, w4, g4, b4, h4, 128);

    pool3x3_kernel<<<72, 256, 0, stream>>>(h4, p2);
    conv5_kernel<<<dim3(4, 16), 256, 0, stream>>>(p2, w5, g5, b5, h5);
    fc_kernel<<<512, 256, 0, stream>>>(h5, wfc, fts);
    attn_kernel<<<128, 256, 0, stream>>>(fts, mixw, outp);
}

// Round 13
// 1643.390 us; speedup vs baseline: 3.8565x; 1.1130x over previous
//
#include <hip/hip_runtime.h>
#include <math.h>

// ---------------------------------------------------------------------------
// BivariateNormalAttention pipeline.
// Round 12: R11 + conv1 also 2-product (numerics justified by R11's
//   bit-identical absmax when the same trick was applied to conv2):
//   - presplit_x stores x as RNE bf16 HI ONLY (unbiased ~2^-9 rel, same
//     error mechanism R11 proved invisible at h1; xs halves to 206MB).
//   - conv1 == conv2 structure: A single-plane (sA 21.5KB, 8 A-reads/tap),
//     64 MFMA/tap/wave, weights exact hi+lo (AhBh+AhBl) in BOTH convs.
//   - same-acc MFMA chains reordered to distance 4 (was 1).
//   - R7's verified staging/sync: 2 independent 4-wave blocks/CU, 2-tap B
//     staging (2x16KB), 10 barriers/chunk, conflict-free swizzles.
// ---------------------------------------------------------------------------

typedef __attribute__((ext_vector_type(8))) short short8v;
typedef __attribute__((ext_vector_type(4))) float f32x4;

__device__ __forceinline__ void split_bf16(float f, unsigned int& hi, unsigned int& lo)
{
    unsigned int u = __float_as_uint(f);
    hi = u >> 16;                                    // truncated bf16 hi
    float hif = __uint_as_float(u & 0xffff0000u);
    lo = __float_as_uint(f - hif) >> 16;             // residual, truncated
}

__device__ __forceinline__ unsigned int rne_bf16(float f)
{
    unsigned int u = __float_as_uint(f);
    u += 0x7fffu + ((u >> 16) & 1u);                 // round-to-nearest-even
    return u >> 16;
}

__device__ __forceinline__ void gld16(const void* g, void* l)
{
    __builtin_amdgcn_global_load_lds(
        (const __attribute__((address_space(1))) unsigned int*)g,
        (__attribute__((address_space(3))) unsigned int*)l, 16, 0, 0);
}

__global__ void zero_kernel(float* z) { z[threadIdx.x] = 0.f; }

// wp[y2][ch][tap][pl2][co128][k32] u16; within each co's 64B row the 16B
// quarters are pre-swizzled: phys quarter qp holds logical q = qp ^ ((co>>1)&3).
__global__ __launch_bounds__(256)
void prep_w_kernel(const float* __restrict__ w, unsigned short* __restrict__ wp, int CIN)
{
    int idx = blockIdx.x * 256 + threadIdx.x;
    int NCH = CIN >> 5;
    int total = 2 * NCH * 9 * 2 * 128 * 32;
    if (idx >= total) return;
    int kk = idx & 31;
    int co = (idx >> 5) & 127;
    int pl = (idx >> 12) & 1;
    int rest = idx >> 13;            // (y*NCH + ch)*9 + tap
    int tap = rest % 9;
    rest /= 9;
    int ch = rest % NCH;
    int y = rest / NCH;
    int qp = kk >> 3, e = kk & 7;
    int q = qp ^ ((co >> 1) & 3);
    int ci = ch * 32 + q * 8 + e;
    int cog = y * 128 + co;
    float f = w[((size_t)cog * CIN + ci) * 9 + tap];
    unsigned int hi, lo;
    split_bf16(f, hi, lo);
    wp[idx] = (unsigned short)(pl ? lo : hi);
}

// x[b][512][112][112] f32 -> xs[b][16ch][112][112][32ci] RNE bf16 (hi only),
// quarters pre-swizzled by pixel: qp = q ^ ((18*gy+gx+19)>>1 & 3)
__global__ __launch_bounds__(256)
void presplit_x_kernel(const float* __restrict__ x, unsigned short* __restrict__ xs)
{
    const int gy = blockIdx.x, ch = blockIdx.y, b = blockIdx.z;
    const int tid = threadIdx.x;
    __shared__ float s[32][113];
    for (int i = tid; i < 32 * 112; i += 256) {
        int ci = i / 112, xx = i - ci * 112;
        s[ci][xx] = x[(((size_t)(b * 16 + ch) * 32 + ci) * 112 + gy) * 112 + xx];
    }
    __syncthreads();
    unsigned int* oh = (unsigned int*)(xs + ((size_t)(b * 16 + ch) * 12544 + (size_t)gy * 112) * 32);
    for (int i = tid; i < 112 * 16; i += 256) {
        int px = i >> 4, t = i & 15;          // t = u32 slot within 64B row
        int qp = t >> 2, ep = t & 3;
        int sw = ((18 * gy + px + 19) >> 1) & 3;
        int q = qp ^ sw;
        int ci0 = q * 8 + ep * 2;
        oh[(size_t)px * 16 + t] = rne_bf16(s[ci0][px]) | (rne_bf16(s[ci0 + 1][px]) << 16);
    }
}

// POOL=false: conv1 (xs RNE hi) -> h1s hi-only RNE bf16.
// POOL=true : conv2 (h1s hi)    -> pooled fp32 [B,256,7,7].
// Both: 2-product (AhBh + AhBl), A single-plane.
template<int CIN, bool POOL>
__global__ __launch_bounds__(256, 2)
void conv_mfma_kernel(const unsigned short* __restrict__ xs,
                      const unsigned short* __restrict__ wp,
                      const float* __restrict__ gam, const float* __restrict__ bet,
                      void* __restrict__ out_, const float* __restrict__ zerob)
{
    constexpr int NCH = CIN >> 5;
    extern __shared__ __align__(16) char smem[];   // 54272 B
    char* sA = smem;                 // 21504: [336px][64B] (324 used)
    char* sB = smem + 21504;         // 2 x 16384: [half][pl2][co128][64B]

    const int tid = threadIdx.x;
    const int lane = tid & 63;
    const int wv = tid >> 6;
    const int wvm = wv >> 1, ng = wv & 1;
    const int m = lane & 15, kg = lane >> 4;
    const int ty = blockIdx.x / 7, tx = blockIdx.x % 7;
    const int yb = blockIdx.y;
    const int b = blockIdx.z;

    // ---- A staging geometry: 21 wave-issues of 1KB, round-robin over 4 waves
    int aoff[6];
    unsigned adst[6];
    #pragma unroll
    for (int k2 = 0; k2 < 6; ++k2) {
        int j = wv + 4 * k2;
        aoff[k2] = -1; adst[k2] = 0;
        if (j < 21) {
            int px = j * 16 + (lane >> 2);
            int py = px / 18, pxx = px - py * 18;
            int gy = ty * 16 + py - 1, gx = tx * 16 + pxx - 1;
            bool valid = (px < 324) && ((unsigned)gy < 112u) && ((unsigned)gx < 112u);
            aoff[k2] = valid ? (((gy * 112 + gx) << 6) + ((lane & 3) << 4)) : -1;
            adst[k2] = j * 1024;
        }
    }
    const char* zb = (const char*)zerob + ((lane & 3) << 4);

    auto issueA = [&](int ch) {
        const char* xbase = (const char*)xs + (size_t)(b * NCH + ch) * 802816;
        #pragma unroll
        for (int k2 = 0; k2 < 6; ++k2) {
            if (wv + 4 * k2 < 21) {
                const char* g = (aoff[k2] >= 0) ? (xbase + aoff[k2]) : zb;
                gld16(g, sA + adst[k2]);
            }
        }
    };
    const char* wbase = (const char*)wp + (size_t)yb * ((size_t)NCH * 9 * 16384);
    auto issueB = [&](int flat, int half) {
        const char* gb = wbase + (size_t)flat * 16384 + (wv << 12) + (lane << 4);
        char* db = sB + half * 16384 + (wv << 12);
        #pragma unroll
        for (int j2 = 0; j2 < 4; ++j2)
            gld16(gb + j2 * 1024, db + j2 * 1024);
    };

    f32x4 acc[8][4];
    #pragma unroll
    for (int i = 0; i < 8; ++i)
        #pragma unroll
        for (int j = 0; j < 4; ++j)
            acc[i][j] = (f32x4){0.f, 0.f, 0.f, 0.f};

    auto mfma_tap = [&](int tap, const char* sBc) {
        const int ky = tap / 3, kx = tap % 3;
        short8v Bh_[4], Bl_[4];
        #pragma unroll
        for (int nf = 0; nf < 4; ++nf) {
            int col = ng * 64 + nf * 16 + m;
            int off = col * 64 + ((kg ^ ((col >> 1) & 3)) << 4);
            Bh_[nf] = *(const short8v*)(sBc + off);
            Bl_[nf] = *(const short8v*)(sBc + 8192 + off);
        }
        #pragma unroll
        for (int mf = 0; mf < 8; ++mf) {
            int ap = (wvm * 8 + mf + ky) * 18 + kx + m;
            int off = ap * 64 + ((kg ^ ((ap >> 1) & 3)) << 4);
            short8v Ah = *(const short8v*)(sA + off);
            // same-acc chains at distance 4
            #pragma unroll
            for (int nf = 0; nf < 4; ++nf)
                acc[mf][nf] = __builtin_amdgcn_mfma_f32_16x16x32_bf16(Ah, Bh_[nf], acc[mf][nf], 0, 0, 0);
            #pragma unroll
            for (int nf = 0; nf < 4; ++nf)
                acc[mf][nf] = __builtin_amdgcn_mfma_f32_16x16x32_bf16(Ah, Bl_[nf], acc[mf][nf], 0, 0, 0);
        }
    };

    // prologue: A(0), B taps {0,1} of chunk 0
    issueA(0);
    issueB(0, 0);
    issueB(1, 1);
    asm volatile("s_waitcnt vmcnt(0)" ::: "memory");
    __syncthreads();

    for (int ch = 0; ch < NCH; ++ch) {
        const int base = ch * 9;
        // 4 tap-pairs: (0,1) (2,3) (4,5) (6,7)
        #pragma unroll
        for (int pe = 0; pe < 4; ++pe) {
            mfma_tap(2 * pe, sB);
            mfma_tap(2 * pe + 1, sB + 16384);
            __syncthreads();                 // done reading both sB halves
            if (pe < 3) {
                issueB(base + 2 * pe + 2, 0);
                issueB(base + 2 * pe + 3, 1);
            } else {
                issueB(base + 8, 0);         // lone tap 8
            }
            asm volatile("s_waitcnt vmcnt(0)" ::: "memory");
            __syncthreads();
        }
        // tap 8 + chunk edge
        mfma_tap(8, sB);
        __syncthreads();                     // done reading sB half0 and sA
        if (ch + 1 < NCH) {
            issueA(ch + 1);
            issueB(base + 9, 0);             // next chunk taps {0,1}
            issueB(base + 10, 1);
        }
        asm volatile("s_waitcnt vmcnt(0)" ::: "memory");
        __syncthreads();
    }

    const float kRS = 1.0f / sqrtf(1.0f + 1e-5f);

    if (!POOL) {
        // write h1s[b][ch2 8][gy][gx][32] bf16 HI ONLY (RNE), swizzled quarters
        unsigned short* h1s = (unsigned short*)out_;
        #pragma unroll
        for (int mf = 0; mf < 8; ++mf) {
            int gy = ty * 16 + wvm * 8 + mf;
            #pragma unroll
            for (int nf = 0; nf < 4; ++nf) {
                int co = yb * 128 + ng * 64 + nf * 16 + m;
                float sc = gam[co] * kRS, bi = bet[co];
                int ch2 = co >> 5, sl = co & 31, q = sl >> 3, e = sl & 7;
                size_t base2 = (size_t)(b * 8 + ch2) * 401408;   // u16 per (b,ch2)
                #pragma unroll
                for (int r = 0; r < 4; ++r) {
                    int gx = tx * 16 + kg * 4 + r;
                    float v = fmaxf(fmaf(acc[mf][nf][r], sc, bi), 0.f);
                    int sw = ((18 * gy + gx + 19) >> 1) & 3;
                    size_t po = base2 + ((size_t)gy * 112 + gx) * 32 + (size_t)((q ^ sw) * 8 + e);
                    h1s[po] = (unsigned short)rne_bf16(v);
                }
            }
        }
    } else {
        // fused BN+ReLU + 16x16 avg pool (tile == pool window)
        __syncthreads();                      // all waves past the last barrier
        float* spool = (float*)smem;          // 4 waves x 4 nf x 16 co floats
        #pragma unroll
        for (int nf = 0; nf < 4; ++nf) {
            int co = yb * 128 + ng * 64 + nf * 16 + m;
            float sc = gam[co] * kRS, bi = bet[co];
            float s = 0.f;
            #pragma unroll
            for (int mf = 0; mf < 8; ++mf)
                #pragma unroll
                for (int r = 0; r < 4; ++r)
                    s += fmaxf(fmaf(acc[mf][nf][r], sc, bi), 0.f);
            s += __shfl_xor(s, 16);
            s += __shfl_xor(s, 32);
            if (lane < 16) spool[(wv * 4 + nf) * 16 + lane] = s;
        }
        __syncthreads();
        if (tid < 128) {
            // tid = ngx*64 + nf*16 + m : co within the yb half
            int ngx = tid >> 6, rem = tid & 63;
            int nf = rem >> 4, mm = rem & 15;
            float s = spool[(ngx * 4 + nf) * 16 + mm] + spool[((2 + ngx) * 4 + nf) * 16 + mm];
            float* p1o = (float*)out_;
            p1o[(((size_t)b * 256 + yb * 128 + tid) * 7 + ty) * 7 + tx] = s * (1.f / 256.f);
        }
    }
}

// ---------------- small downstream stages ----------------------------------

template<int CIN>
__global__ __launch_bounds__(256)
void conv_small_kernel(const float* __restrict__ in, const float* __restrict__ w,
                       const float* __restrict__ gam, const float* __restrict__ bet,
                       float* __restrict__ out, int CO_TOT)
{
    const int co0 = blockIdx.x * 16;
    const int b = blockIdx.y;
    const int tid = threadIdx.x;
    const int px = tid & 63;
    const int wg = tid >> 6;
    const int py = px / 7, pxx = px - py * 7;
    const bool act = px < 49;

    __shared__ float s_in[64][9][9];
    __shared__ float s_w[64][16][9];

    float acc[4] = {0.f, 0.f, 0.f, 0.f};

    for (int ci0 = 0; ci0 < CIN; ci0 += 64) {
        __syncthreads();
        for (int idx = tid; idx < 64 * 81; idx += 256) {
            int ci = idx / 81;
            int rem = idx - ci * 81;
            int r = rem / 9, c = rem - (rem / 9) * 9;
            float v = 0.f;
            if (r >= 1 && r <= 7 && c >= 1 && c <= 7)
                v = in[((size_t)(b * CIN + ci0 + ci) * 7 + (r - 1)) * 7 + (c - 1)];
            s_in[ci][r][c] = v;
        }
        for (int idx = tid; idx < 64 * 16 * 9; idx += 256) {
            int co = idx / 576;
            int rem = idx - co * 576;
            int ci = rem / 9, tap = rem - (rem / 9) * 9;
            s_w[ci][co][tap] = w[((size_t)(co0 + co) * CIN + ci0 + ci) * 9 + tap];
        }
        __syncthreads();
        if (act) {
            for (int ci = 0; ci < 64; ++ci) {
                #pragma unroll
                for (int ky = 0; ky < 3; ++ky)
                    #pragma unroll
                    for (int kx = 0; kx < 3; ++kx) {
                        float v = s_in[ci][py + ky][pxx + kx];
                        #pragma unroll
                        for (int j = 0; j < 4; ++j)
                            acc[j] = fmaf(v, s_w[ci][wg * 4 + j][ky * 3 + kx], acc[j]);
                    }
            }
        }
    }
    if (act) {
        const float kRS = 1.0f / sqrtf(1.0f + 1e-5f);
        #pragma unroll
        for (int j = 0; j < 4; ++j) {
            int cog = co0 + wg * 4 + j;
            float v = fmaxf(fmaf(acc[j], gam[cog] * kRS, bet[cog]), 0.f);
            out[(size_t)(b * CO_TOT + cog) * 49 + py * 7 + pxx] = v;
        }
    }
}

__global__ void pool3x3_kernel(const float* __restrict__ in, float* __restrict__ out)
{
    int o = blockIdx.x * 256 + threadIdx.x;
    if (o >= 16 * 128 * 9) return;
    int xo = o % 3;
    int yo = (o / 3) % 3;
    int bc = o / 9;
    const float* p = in + (size_t)bc * 49;
    float s = 0.f;
    #pragma unroll
    for (int ky = 0; ky < 3; ++ky)
        #pragma unroll
        for (int kx = 0; kx < 3; ++kx)
            s += p[(yo * 2 + ky) * 7 + xo * 2 + kx];
    out[o] = s * (1.0f / 9.0f);
}

__global__ __launch_bounds__(256)
void conv5_kernel(const float* __restrict__ in, const float* __restrict__ w,
                  const float* __restrict__ gam, const float* __restrict__ bet,
                  float* __restrict__ out)
{
    const int co0 = blockIdx.x * 16;
    const int b = blockIdx.y;
    const int tid = threadIdx.x;
    __shared__ float s_in[128][5][5];
    __shared__ float s_w[64][16][9];

    for (int idx = tid; idx < 128 * 25; idx += 256) {
        int ci = idx / 25;
        int rem = idx - ci * 25;
        int r = rem / 5, c = rem - (rem / 5) * 5;
        float v = 0.f;
        if (r >= 1 && r <= 3 && c >= 1 && c <= 3)
            v = in[((size_t)(b * 128 + ci) * 3 + (r - 1)) * 3 + (c - 1)];
        s_in[ci][r][c] = v;
    }

    float acc = 0.f;
    const int co = tid / 9;
    const int px = tid - co * 9;
    const int pyy = px / 3, pxx = px - pyy * 3;
    const bool act = tid < 144;

    for (int ci0 = 0; ci0 < 128; ci0 += 64) {
        __syncthreads();
        for (int idx = tid; idx < 64 * 16 * 9; idx += 256) {
            int c2 = idx / 576;
            int rem = idx - c2 * 576;
            int ci = rem / 9, tap = rem - (rem / 9) * 9;
            s_w[ci][c2][tap] = w[((size_t)(co0 + c2) * 128 + ci0 + ci) * 9 + tap];
        }
        __syncthreads();
        if (act) {
            for (int ci = 0; ci < 64; ++ci) {
                #pragma unroll
                for (int ky = 0; ky < 3; ++ky)
                    #pragma unroll
                    for (int kx = 0; kx < 3; ++kx)
                        acc = fmaf(s_in[ci0 + ci][pyy + ky][pxx + kx],
                                   s_w[ci][co][ky * 3 + kx], acc);
            }
        }
    }
    if (act) {
        const float kRS = 1.0f / sqrtf(1.0f + 1e-5f);
        int cog = co0 + co;
        out[(size_t)(b * 64 + cog) * 9 + px] =
            fmaxf(fmaf(acc, gam[cog] * kRS, bet[cog]), 0.f);
    }
}

// fc: 512 blocks x 256 threads; 4 outputs/block, 64 lanes per output.
__global__ __launch_bounds__(256)
void fc_kernel(const float* __restrict__ h5, const float* __restrict__ wfc,
               float* __restrict__ feats)
{
    int o = blockIdx.x * 4 + (threadIdx.x >> 6);
    int lane = threadIdx.x & 63;
    int b = o >> 7, j = o & 127;
    const float* hp = h5 + b * 576;
    const float* wp = wfc + j * 576;
    float s = 0.f;
    for (int k = lane; k < 576; k += 64) s = fmaf(hp[k], wp[k], s);
    #pragma unroll
    for (int off = 32; off > 0; off >>= 1) s += __shfl_down(s, off);
    if (lane == 0) feats[o] = s;
}

__global__ __launch_bounds__(256)
void attn_kernel(const float* __restrict__ feats, const float* __restrict__ mixw,
                 float* __restrict__ out)
{
    const int bo = blockIdx.x;
    const int b = bo >> 3, o = bo & 7;
    const int tid = threadIdx.x;
    __shared__ float s_att[4][3136];
    __shared__ float s_red[4];

    float mv[4];
    float mmax = -1e30f;
    #pragma unroll
    for (int g = 0; g < 4; ++g) { mv[g] = mixw[o * 4 + g]; mmax = fmaxf(mmax, mv[g]); }
    float msum = 0.f;
    #pragma unroll
    for (int g = 0; g < 4; ++g) { mv[g] = expf(mv[g] - mmax); msum += mv[g]; }
    #pragma unroll
    for (int g = 0; g < 4; ++g) mv[g] /= msum;

    const float LOG_R = 1.0986122886681098f;
    float winv[4];
    for (int g = 0; g < 4; ++g) {
        float f0 = feats[b * 128 + o * 16 + g * 4 + 0];
        float f1 = feats[b * 128 + o * 16 + g * 4 + 1];
        float f2 = feats[b * 128 + o * 16 + g * 4 + 2];
        float f3 = feats[b * 128 + o * 16 + g * 4 + 3];
        float m_x = 55.f / (1.f + expf(-f0));
        float m_y = 55.f / (1.f + expf(-f1));
        float r = expf((2.f / (1.f + expf(-f2)) - 1.f) * LOG_R);
        float rho = 1.6f / (1.f + expf(-f3)) - 0.8f;
        float denom = (-0.5f / (1.f - rho * rho)) * (1.f / 3136.f);
        float rin = 1.f / r;

        float ssum = 0.f;
        for (int p = tid; p < 3136; p += 256) {
            int i = p / 56;
            int j = p - i * 56;
            float dx = m_x - (float)i;
            float dy = m_y - (float)j;
            float quad = dx * dx * r + dy * dy * rin - 2.f * rho * dx * dy;
            float e = expf(denom * quad);
            s_att[g][p] = e;
            ssum += e;
        }
        #pragma unroll
        for (int off = 32; off > 0; off >>= 1) ssum += __shfl_down(ssum, off);
        if ((tid & 63) == 0) s_red[tid >> 6] = ssum;
        __syncthreads();
        winv[g] = mv[g] / (s_red[0] + s_red[1] + s_red[2] + s_red[3]);
        __syncthreads();
    }

    for (int p = tid; p < 3136; p += 256) {
        float v = 0.f;
        #pragma unroll
        for (int g = 0; g < 4; ++g) v += s_att[g][p] * winv[g];
        out[(size_t)bo * 3136 + p] = v;
    }
}

// ---------------------------------------------------------------------------

extern "C" void kernel_launch(void* const* d_in, const int* in_sizes, int n_in,
                              void* d_out, int out_size, void* d_ws, size_t ws_size,
                              hipStream_t stream)
{
    const float* x    = (const float*)d_in[0];
    const float* w1   = (const float*)d_in[1];
    const float* g1   = (const float*)d_in[2];
    const float* b1   = (const float*)d_in[3];
    const float* w2   = (const float*)d_in[4];
    const float* g2   = (const float*)d_in[5];
    const float* b2   = (const float*)d_in[6];
    const float* w3   = (const float*)d_in[7];
    const float* g3   = (const float*)d_in[8];
    const float* b3   = (const float*)d_in[9];
    const float* w4   = (const float*)d_in[10];
    const float* g4   = (const float*)d_in[11];
    const float* b4   = (const float*)d_in[12];
    const float* w5   = (const float*)d_in[13];
    const float* g5   = (const float*)d_in[14];
    const float* b5   = (const float*)d_in[15];
    const float* wfc  = (const float*)d_in[16];
    const float* mixw = (const float*)d_in[17];
    float* outp = (float*)d_out;

    // dynamic-LDS opt-in (immediate host call, deterministic, capture-safe)
    hipFuncSetAttribute(reinterpret_cast<const void*>(&conv_mfma_kernel<512, false>),
                        hipFuncAttributeMaxDynamicSharedMemorySize, 54272);
    hipFuncSetAttribute(reinterpret_cast<const void*>(&conv_mfma_kernel<256, true>),
                        hipFuncAttributeMaxDynamicSharedMemorySize, 54272);

    // workspace layout (bytes)
    char* wsb = (char*)d_ws;
    unsigned short* wp = (unsigned short*)wsb;   wsb += (size_t)2359296 * 2;      // 4.7MB (reused)
    unsigned short* xs = (unsigned short*)wsb;   wsb += (size_t)16*16*12544*32*2;    // 205.5MB (hi only)
    unsigned short* h1s = (unsigned short*)wsb;  wsb += (size_t)16*8*12544*32*2;     // 102.8MB (hi only)
    float* p1 = (float*)wsb;  wsb += 200704 * 4;
    float* h3 = (float*)wsb;  wsb += 100352 * 4;
    float* h4 = (float*)wsb;  wsb += 100352 * 4;
    float* p2 = (float*)wsb;  wsb += 18432 * 4;
    float* h5 = (float*)wsb;  wsb += 9216 * 4;
    float* fts = (float*)wsb; wsb += 2048 * 4;
    float* zerob = (float*)wsb; wsb += 64 * 4;

    zero_kernel<<<1, 64, 0, stream>>>(zerob);
    presplit_x_kernel<<<dim3(112, 16, 16), 256, 0, stream>>>(x, xs);

    prep_w_kernel<<<9216, 256, 0, stream>>>(w1, wp, 512);
    conv_mfma_kernel<512, false><<<dim3(49, 2, 16), 256, 54272, stream>>>(xs, wp, g1, b1, h1s, zerob);

    prep_w_kernel<<<4608, 256, 0, stream>>>(w2, wp, 256);
    conv_mfma_kernel<256, true><<<dim3(49, 2, 16), 256, 54272, stream>>>(h1s, wp, g2, b2, p1, zerob);

    conv_small_kernel<256><<<dim3(8, 16), 256, 0, stream>>>(p1, w3, g3, b3, h3, 128);
    conv_small_kernel<128><<<dim3(8, 16), 256, 0, stream>>>(h3, w4, g4, b4, h4, 128);

    pool3x3_kernel<<<72, 256, 0, stream>>>(h4, p2);
    conv5_kernel<<<dim3(4, 16), 256, 0, stream>>>(p2, w5, g5, b5, h5);
    fc_kernel<<<512, 256, 0, stream>>>(h5, wfc, fts);
    attn_kernel<<<128, 256, 0, stream>>>(fts, mixw, outp);
}